// Round 10
// baseline (161.251 us; speedup 1.0000x reference)
//
#include <hip/hip_runtime.h>
#include <hip/hip_bf16.h>
#include <math.h>

// ================= complex 2x2 helpers (prep only) =================
struct cf { float x, y; };
__device__ __forceinline__ cf cfmul(cf a, cf b){ return {a.x*b.x - a.y*b.y, a.x*b.y + a.y*b.x}; }
__device__ __forceinline__ cf cfconj(cf a){ return {a.x, -a.y}; }
__device__ __forceinline__ cf cfadd(cf a, cf b){ return {a.x+b.x, a.y+b.y}; }

__device__ __forceinline__ void pmat(int k, cf* P){
    if (k==0){ P[0]={1.f,0.f}; P[1]={0.f,0.f}; P[2]={0.f,0.f}; P[3]={1.f,0.f}; }
    else if (k==1){ P[0]={0.f,0.f}; P[1]={1.f,0.f}; P[2]={1.f,0.f}; P[3]={0.f,0.f}; }
    else if (k==2){ P[0]={0.f,0.f}; P[1]={0.f,-1.f}; P[2]={0.f,1.f}; P[3]={0.f,0.f}; }
    else { P[0]={1.f,0.f}; P[1]={0.f,0.f}; P[2]={0.f,0.f}; P[3]={-1.f,0.f}; }
}
__device__ void mul2(cf* C, const cf* A, const cf* B){
    C[0]=cfadd(cfmul(A[0],B[0]),cfmul(A[1],B[2]));
    C[1]=cfadd(cfmul(A[0],B[1]),cfmul(A[1],B[3]));
    C[2]=cfadd(cfmul(A[2],B[0]),cfmul(A[3],B[2]));
    C[3]=cfadd(cfmul(A[2],B[1]),cfmul(A[3],B[3]));
}
// T[t*4+s] += 0.5 * Re tr(P_t K P_s K^dagger)
__device__ void ptm_acc(float* T, const cf* K){
    cf Kd[4] = {cfconj(K[0]), cfconj(K[2]), cfconj(K[1]), cfconj(K[3])};
    for (int s=0;s<4;s++){
        cf Ps[4]; pmat(s,Ps);
        cf t1[4], t2[4];
        mul2(t1, K, Ps);
        mul2(t2, t1, Kd);
        for (int t=0;t<4;t++){
            cf Pt[4]; pmat(t,Pt);
            float re = Pt[0].x*t2[0].x - Pt[0].y*t2[0].y
                     + Pt[1].x*t2[2].x - Pt[1].y*t2[2].y
                     + Pt[2].x*t2[1].x - Pt[2].y*t2[1].y
                     + Pt[3].x*t2[3].x - Pt[3].y*t2[3].y;
            T[t*4+s] += 0.5f*re;
        }
    }
}
__device__ void rmm4(float* C, const float* A, const float* B){
    for (int i=0;i<4;i++) for (int j=0;j<4;j++){
        float s=0.f;
        for (int k=0;k<4;k++) s += A[i*4+k]*B[k*4+j];
        C[i*4+j]=s;
    }
}

// in-kernel prep: threads 0..30 fill sm[0..495] with REAL Pauli-transfer mats.
// sm[(l*10+q)*16..] = Tnoise1 * Trot(l,q); sm[480..] = Tnoise2 (N2).
__device__ void prep_sm(float* sm, const float* __restrict__ wts, int tid){
    if (tid < 31){
        const float GA = -expm1f(-2.0000000000000002e-06f);   // 1-exp(-GATE/T1)
        const float GP = -expm1f(-1.4285714285714286e-06f);   // 1-exp(-GATE/T2)
        float sa = sqrtf(1.f-GA), spp = sqrtf(1.f-GP);
        float p = (tid==30) ? 0.01f : 0.001f;
        float f = 1.f - (4.f/3.f)*p;
        float Tn[16] = {0};
        Tn[0]      = 1.f;
        Tn[1*4+1]  = spp*sa*f;
        Tn[2*4+2]  = spp*sa*f;
        Tn[3*4+3]  = (1.f-GA)*f;
        Tn[3*4+0]  = GA;
        if (tid == 30){
            for (int i=0;i<16;i++) sm[480+i] = Tn[i];
        } else {
            float phi = wts[tid*3+0], th = wts[tid*3+1], om = wts[tid*3+2];
            float ct = cosf(0.5f*th), st = sinf(0.5f*th);
            cf ep = {cosf(0.5f*(phi+om)), -sinf(0.5f*(phi+om))};
            cf em = {cosf(0.5f*(phi-om)),  sinf(0.5f*(phi-om))};
            cf U[4];
            U[0] = { ep.x*ct,  ep.y*ct};
            U[1] = {-em.x*st, -em.y*st};
            U[2] = { em.x*st, -em.y*st};
            U[3] = { ep.x*ct, -ep.y*ct};
            float Tr[16] = {0};
            ptm_acc(Tr, U);                 // unitary: single Kraus
            float S[16]; rmm4(S, Tn, Tr);   // rot first, then noise
            for (int i=0;i<16;i++) sm[tid*16+i] = S[i];
        }
    }
}

// LDS swizzle on 12-bit float index: XOR bits 9..11 into 2..4 (float4-preserving)
__device__ __forceinline__ unsigned swz(unsigned t){ return t ^ ((t>>7)&0x1Cu); }

#define ALONG_A(Mp) { _Pragma("unroll") for (int db_=0; db_<4; db_++){ \
    float a0=v[db_], a1=v[4+db_], a2=v[8+db_], a3=v[12+db_]; \
    _Pragma("unroll") for (int dp_=0; dp_<4; dp_++){ \
        v[dp_*4+db_] = (Mp)[dp_*4+0]*a0 + (Mp)[dp_*4+1]*a1 + (Mp)[dp_*4+2]*a2 + (Mp)[dp_*4+3]*a3; } } }

#define ALONG_B(Mp) { _Pragma("unroll") for (int da_=0; da_<4; da_++){ \
    float a0=v[da_*4+0], a1=v[da_*4+1], a2=v[da_*4+2], a3=v[da_*4+3]; \
    _Pragma("unroll") for (int dp_=0; dp_<4; dp_++){ \
        v[da_*4+dp_] = (Mp)[dp_*4+0]*a0 + (Mp)[dp_*4+1]*a1 + (Mp)[dp_*4+2]*a2 + (Mp)[dp_*4+3]*a3; } } }

// shared op-chain (5 ops of one phase window). ISB selects bit tables; LAYER selects mats.
template<int LAYER, int ISB>
__device__ __forceinline__ void run_ops(float* tile, const float* sm, int tid){
    constexpr int A_PA[5] = {0,10,8,6,4}, A_PB[5] = {10,8,6,4,2};
    constexpr int B_PA[5] = {2,10,8,6,4}, B_PB[5] = {10,8,6,4,0};
#pragma unroll
    for (int i=0; i<5; i++){
        const int pa = ISB ? B_PA[i] : A_PA[i];
        const int pb = ISB ? B_PB[i] : A_PB[i];
        const int mA = (!ISB && i==0) ? LAYER*160 : -1;               // rot(l,0) on control
        const int mB = !ISB ? (LAYER*10 + i + 1)*16
                            : ((i < 4) ? (LAYER*10 + 6 + i)*16 : -1); // rot(l,6..9)
        const int lo = pa < pb ? pa : pb, hi = pa < pb ? pb : pa;
        unsigned g8 = (unsigned)tid;
        unsigned xx = ((g8 >> lo) << (lo+2)) | (g8 & ((1u<<lo)-1u));
        xx = ((xx >> hi) << (hi+2)) | (xx & ((1u<<hi)-1u));
        unsigned adr[16];
        float v[16];
#pragma unroll
        for (int d=0; d<16; d++){
            unsigned t = xx | ((unsigned)(d>>2) << pa) | ((unsigned)(d&3) << pb);
            adr[d] = swz(t);
            v[d] = tile[adr[d]];
        }
        if (mA >= 0){ const float* M = sm + mA; ALONG_A(M); }
        if (mB >= 0){ const float* M = sm + mB; ALONG_B(M); }
        { // CNOT Pauli-basis signed permutation
            float t0;
            t0=v[4];  v[4]=v[5];   v[5]=t0;
            t0=v[8];  v[8]=v[9];   v[9]=t0;
            t0=v[2];  v[2]=v[14];  v[14]=t0;
            t0=v[3];  v[3]=v[15];  v[15]=t0;
            t0=v[6];  v[6]=v[11];  v[11]=t0;
            t0=v[7];  v[7]=-v[10]; v[10]=-t0;
        }
        { const float* M = sm + 480; ALONG_B(M); ALONG_A(M); }   // N2 target, N2 control
#pragma unroll
        for (int d=0; d<16; d++) tile[adr[d]] = v[d];
        __syncthreads();
    }
}

// ================= sim phase kernel (Pauli rep, fully specialized) =================
// Phase A (ISB=0): tile = bits 0..11 (qubits 0,5,4,3,2,1); block -> bits 12..19.
// Phase B (ISB=1): tile = bits 0..3 + 12..19 (qubits 0,5,9,8,7,6); block -> bits 4..11.
// MODE 3 (P4 = last A phase): store only the 9 LUT windows' entries; zero ready/ticket.
template<int LAYER, int ISB, int DOINIT, int MODE>
__global__ void __launch_bounds__(256)
fused6(float* __restrict__ rho, const float* __restrict__ wts, unsigned* __restrict__ sync)
{
    __shared__ __align__(16) float tile[4096];
    __shared__ float sm[31*16];
    int tid = threadIdx.x;
    unsigned blk = blockIdx.x;

    prep_sm(sm, wts, tid);      // wave 0 only; waves 1-3 fall through to loads

    unsigned bo = blk << (ISB ? 4 : 12);
    if (DOINIT){
        // c_s = 1 for s in {I,Z}^10 (digit bits equal), else 0
#pragma unroll
        for (int r=0; r<16; r++){
            unsigned u = tid + 256u*r;
            unsigned g = u | bo;
            unsigned e = g & 0x55555u, o = (g>>1) & 0x55555u;
            tile[swz(u)] = (e==o) ? 1.f : 0.f;
        }
    } else {
#pragma unroll
        for (int r=0; r<4; r++){
            unsigned u = 4u*(tid + 256u*r);
            unsigned g = ISB ? ((u & 15u) | ((u>>4)<<12) | bo) : (u | bo);
            *reinterpret_cast<float4*>(&tile[swz(u)]) = *reinterpret_cast<const float4*>(rho + g);
        }
    }
    __syncthreads();

    run_ops<LAYER, ISB>(tile, sm, tid);

    if (MODE == 3){
        // only the 9 trace windows of the final B phase consume this output:
        // entries with global bits 4..11 (tile-local here) in the LUT set.
        if (blk == 0 && tid == 0){ sync[0] = 0u; sync[1] = 0u; }   // ready, ticket
        if (tid < 36){
            const unsigned LUT9[9] = {0,1,3,4,12,16,48,64,192};
            unsigned u = (LUT9[tid>>2] << 4) | ((tid & 3u) << 2);
            *reinterpret_cast<float4*>(rho + (u | bo)) =
                *reinterpret_cast<const float4*>(&tile[swz(u)]);
        }
        return;
    }

#pragma unroll
    for (int r=0; r<4; r++){
        unsigned u = 4u*(tid + 256u*r);
        unsigned g = ISB ? ((u & 15u) | ((u>>4)<<12) | bo) : (u | bo);
        *reinterpret_cast<float4*>(rho + g) = *reinterpret_cast<const float4*>(&tile[swz(u)]);
    }
}

// ================= mega tail: P5 (9 ticket-claimed producer blocks) + feats + combine =================
__global__ void __launch_bounds__(256)
mega_tail(float* __restrict__ rho, const float* __restrict__ wts,
          float* __restrict__ cvec, unsigned* __restrict__ sync,
          const float* __restrict__ x, const float* __restrict__ bvec,
          const float* __restrict__ w, float* __restrict__ out)
{
    __shared__ __align__(16) float tile[4096];   // producers: window tile; then reused as xs[1024]
    __shared__ float sm[31*16];
    __shared__ float redl[80];                   // 4 waves x 20 feats
    __shared__ unsigned sticket;
    int tid = threadIdx.x;
    unsigned bid = blockIdx.x;

    // ---- ticket claim: first 9 blocks to run become trace producers (no dispatch-order assumption) ----
    if (tid == 0)
        sticket = __hip_atomic_fetch_add(&sync[1], 1u, __ATOMIC_RELAXED, __HIP_MEMORY_SCOPE_AGENT);
    __syncthreads();
    unsigned t = sticket;

    if (t < 9u){
        const unsigned LUT9[9] = {0,1,3,4,12,16,48,64,192};
        unsigned blk = LUT9[t];
        prep_sm(sm, wts, tid);
        unsigned bo = blk << 4;
#pragma unroll
        for (int r=0; r<4; r++){
            unsigned u = 4u*(tid + 256u*r);
            unsigned g = (u & 15u) | ((u>>4)<<12) | bo;
            *reinterpret_cast<float4*>(&tile[swz(u)]) = *reinterpret_cast<const float4*>(rho + g);
        }
        __syncthreads();
        run_ops<2, 1>(tile, sm, tid);
        // trace extract: exps are single coefficients of weight-1 Pauli strings.
        // Tile slot i -> qubit {0,5,9,8,7,6}; block digit j -> qubit {4,3,2,1}.
        if (blk == 0){
            if (tid < 12){
                const int TQ[6] = {0,5,9,8,7,6};
                int i = tid >> 1, isZ = tid & 1;
                unsigned u = (isZ ? 3u : 1u) << (2*i);
                cvec[2*TQ[i] + isZ] = tile[swz(u)];
            }
        } else if (tid == 0){
            const int BQ[4] = {4,3,2,1};
#pragma unroll
            for (int j=0; j<4; j++){
                if (blk == (1u<<(2*j))) cvec[2*BQ[j]]   = tile[0];
                if (blk == (3u<<(2*j))) cvec[2*BQ[j]+1] = tile[0];
            }
        }
        __syncthreads();
        if (tid == 0){
            __threadfence();   // write back dirty L2 (cvec) to LLC
            __hip_atomic_fetch_add(&sync[0], 1u, __ATOMIC_RELEASE, __HIP_MEMORY_SCOPE_AGENT);
        }
        __syncthreads();       // before reusing tile as xs
    }

    // ---- all blocks: Pauli feats for batch b = bid (independent of cvec) ----
    float* xs = tile;
    {
        float4 xv = reinterpret_cast<const float4*>(x + (size_t)bid*1024)[tid];
        float4 bv = reinterpret_cast<const float4*>(bvec)[tid];
        xs[tid*4+0] = xv.x + bv.x;
        xs[tid*4+1] = xv.y + bv.y;
        xs[tid*4+2] = xv.z + bv.z;
        xs[tid*4+3] = xv.w + bv.w;
    }
    __syncthreads();
    float aX[10] = {0,0,0,0,0,0,0,0,0,0};
    float aZ[10] = {0,0,0,0,0,0,0,0,0,0};
#pragma unroll
    for (int r=0; r<4; r++){
        int m = tid + r*256;
        float xm = xs[m];
        float x2 = xm*xm;
#pragma unroll
        for (int q=0; q<10; q++){
            int bit = 1 << (9-q);
            aX[q] += xm * xs[m ^ bit];
            aZ[q] += (m & bit) ? -x2 : x2;
        }
    }
    int lane = tid & 63, wv = tid >> 6;
#pragma unroll
    for (int k=0; k<20; k++){
        float v = (k < 10) ? aX[k] : aZ[k-10];
        v += __shfl_down(v, 32); v += __shfl_down(v, 16); v += __shfl_down(v, 8);
        v += __shfl_down(v, 4);  v += __shfl_down(v, 2);  v += __shfl_down(v, 1);
        if (lane == 0) redl[wv*20 + k] = v;
    }
    __syncthreads();

    if (tid == 0){
        // wait for all 9 trace producers (they never wait -> deadlock-free)
        while (__hip_atomic_load(&sync[0], __ATOMIC_ACQUIRE, __HIP_MEMORY_SCOPE_AGENT) < 9u)
            __builtin_amdgcn_s_sleep(8);
        __threadfence();       // invalidate caches; xs/feats live in LDS, unaffected
        float logit = 0.f;
#pragma unroll
        for (int q=0; q<10; q++){
            float FX = redl[q]    + redl[20+q] + redl[40+q] + redl[60+q];
            float FZ = redl[10+q] + redl[30+q] + redl[50+q] + redl[70+q];
            logit += w[2*q]   * cvec[2*q]   * FX
                   + 0.96f * w[2*q+1] * cvec[2*q+1] * FZ;   // readout bitflip folded into Z
        }
        out[bid] = 1.f / (1.f + expf(-logit));
    }
}

// ================= launch =================
extern "C" void kernel_launch(void* const* d_in, const int* in_sizes, int n_in,
                              void* d_out, int out_size, void* d_ws, size_t ws_size,
                              hipStream_t stream) {
    const float* x    = (const float*)d_in[0];   // [2048,1024]
    const float* bvec = (const float*)d_in[1];   // [1024]
    const float* w    = (const float*)d_in[2];   // [20]
    const float* cw   = (const float*)d_in[3];   // [3,10,3]
    float* out = (float*)d_out;

    char* ws = (char*)d_ws;
    float*    rho  = (float*)ws;                                      // 2^20 floats = 4 MB
    float*    cvec = (float*)(ws + (size_t)(1u<<20)*sizeof(float));   // 20 floats
    unsigned* sync = (unsigned*)(ws + (size_t)(1u<<20)*sizeof(float) + 128);  // [ready, ticket]
    (void)ws_size; (void)in_sizes; (void)n_in; (void)out_size;

    fused6<0,0,1,0><<<256, 256, 0, stream>>>(rho, cw, sync);
    fused6<0,1,0,0><<<256, 256, 0, stream>>>(rho, cw, sync);
    fused6<1,0,0,0><<<256, 256, 0, stream>>>(rho, cw, sync);
    fused6<1,1,0,0><<<256, 256, 0, stream>>>(rho, cw, sync);
    fused6<2,0,0,3><<<256, 256, 0, stream>>>(rho, cw, sync);   // sparse store + zero sync
    mega_tail<<<2048, 256, 0, stream>>>(rho, cw, cvec, sync, x, bvec, w, out);
}

// Round 11
// 95.595 us; speedup vs baseline: 1.6868x; 1.6868x over previous
//
#include <hip/hip_runtime.h>
#include <hip/hip_bf16.h>
#include <math.h>

// ================= complex 2x2 helpers (prep only) =================
struct cf { float x, y; };
__device__ __forceinline__ cf cfmul(cf a, cf b){ return {a.x*b.x - a.y*b.y, a.x*b.y + a.y*b.x}; }
__device__ __forceinline__ cf cfconj(cf a){ return {a.x, -a.y}; }
__device__ __forceinline__ cf cfadd(cf a, cf b){ return {a.x+b.x, a.y+b.y}; }

__device__ __forceinline__ void pmat(int k, cf* P){
    if (k==0){ P[0]={1.f,0.f}; P[1]={0.f,0.f}; P[2]={0.f,0.f}; P[3]={1.f,0.f}; }
    else if (k==1){ P[0]={0.f,0.f}; P[1]={1.f,0.f}; P[2]={1.f,0.f}; P[3]={0.f,0.f}; }
    else if (k==2){ P[0]={0.f,0.f}; P[1]={0.f,-1.f}; P[2]={0.f,1.f}; P[3]={0.f,0.f}; }
    else { P[0]={1.f,0.f}; P[1]={0.f,0.f}; P[2]={0.f,0.f}; P[3]={-1.f,0.f}; }
}
__device__ void mul2(cf* C, const cf* A, const cf* B){
    C[0]=cfadd(cfmul(A[0],B[0]),cfmul(A[1],B[2]));
    C[1]=cfadd(cfmul(A[0],B[1]),cfmul(A[1],B[3]));
    C[2]=cfadd(cfmul(A[2],B[0]),cfmul(A[3],B[2]));
    C[3]=cfadd(cfmul(A[2],B[1]),cfmul(A[3],B[3]));
}
// T[t*4+s] += 0.5 * Re tr(P_t K P_s K^dagger)
__device__ void ptm_acc(float* T, const cf* K){
    cf Kd[4] = {cfconj(K[0]), cfconj(K[2]), cfconj(K[1]), cfconj(K[3])};
    for (int s=0;s<4;s++){
        cf Ps[4]; pmat(s,Ps);
        cf t1[4], t2[4];
        mul2(t1, K, Ps);
        mul2(t2, t1, Kd);
        for (int t=0;t<4;t++){
            cf Pt[4]; pmat(t,Pt);
            float re = Pt[0].x*t2[0].x - Pt[0].y*t2[0].y
                     + Pt[1].x*t2[2].x - Pt[1].y*t2[2].y
                     + Pt[2].x*t2[1].x - Pt[2].y*t2[1].y
                     + Pt[3].x*t2[3].x - Pt[3].y*t2[3].y;
            T[t*4+s] += 0.5f*re;
        }
    }
}
__device__ void rmm4(float* C, const float* A, const float* B){
    for (int i=0;i<4;i++) for (int j=0;j<4;j++){
        float s=0.f;
        for (int k=0;k<4;k++) s += A[i*4+k]*B[k*4+j];
        C[i*4+j]=s;
    }
}

// prep compute: threads 0..30 fill sm[0..495] with REAL Pauli-transfer mats.
// sm[(l*10+q)*16..] = Tnoise1 * Trot(l,q); sm[480..] = Tnoise2 (N2).
__device__ void prep_compute(float* sm, const float* __restrict__ wts, int tid){
    if (tid < 31){
        const float GA = -expm1f(-2.0000000000000002e-06f);   // 1-exp(-GATE/T1)
        const float GP = -expm1f(-1.4285714285714286e-06f);   // 1-exp(-GATE/T2)
        float sa = sqrtf(1.f-GA), spp = sqrtf(1.f-GP);
        float p = (tid==30) ? 0.01f : 0.001f;
        float f = 1.f - (4.f/3.f)*p;
        float Tn[16] = {0};
        Tn[0]      = 1.f;
        Tn[1*4+1]  = spp*sa*f;
        Tn[2*4+2]  = spp*sa*f;
        Tn[3*4+3]  = (1.f-GA)*f;
        Tn[3*4+0]  = GA;
        if (tid == 30){
            for (int i=0;i<16;i++) sm[480+i] = Tn[i];
        } else {
            float phi = wts[tid*3+0], th = wts[tid*3+1], om = wts[tid*3+2];
            float ct = cosf(0.5f*th), st = sinf(0.5f*th);
            cf ep = {cosf(0.5f*(phi+om)), -sinf(0.5f*(phi+om))};
            cf em = {cosf(0.5f*(phi-om)),  sinf(0.5f*(phi-om))};
            cf U[4];
            U[0] = { ep.x*ct,  ep.y*ct};
            U[1] = {-em.x*st, -em.y*st};
            U[2] = { em.x*st, -em.y*st};
            U[3] = { ep.x*ct, -ep.y*ct};
            float Tr[16] = {0};
            ptm_acc(Tr, U);                 // unitary: single Kraus
            float S[16]; rmm4(S, Tn, Tr);   // rot first, then noise
            for (int i=0;i<16;i++) sm[tid*16+i] = S[i];
        }
    }
}

// LDS swizzle on 12-bit float index: XOR bits 9..11 into 2..4 (float4-preserving)
__device__ __forceinline__ unsigned swz(unsigned t){ return t ^ ((t>>7)&0x1Cu); }

#define ALONG_A(Mp) { _Pragma("unroll") for (int db_=0; db_<4; db_++){ \
    float a0=v[db_], a1=v[4+db_], a2=v[8+db_], a3=v[12+db_]; \
    _Pragma("unroll") for (int dp_=0; dp_<4; dp_++){ \
        v[dp_*4+db_] = (Mp)[dp_*4+0]*a0 + (Mp)[dp_*4+1]*a1 + (Mp)[dp_*4+2]*a2 + (Mp)[dp_*4+3]*a3; } } }

#define ALONG_B(Mp) { _Pragma("unroll") for (int da_=0; da_<4; da_++){ \
    float a0=v[da_*4+0], a1=v[da_*4+1], a2=v[da_*4+2], a3=v[da_*4+3]; \
    _Pragma("unroll") for (int dp_=0; dp_<4; dp_++){ \
        v[da_*4+dp_] = (Mp)[dp_*4+0]*a0 + (Mp)[dp_*4+1]*a1 + (Mp)[dp_*4+2]*a2 + (Mp)[dp_*4+3]*a3; } } }

// shared op-chain (5 ops of one phase window). ISB selects bit tables; LAYER selects mats.
template<int LAYER, int ISB>
__device__ __forceinline__ void run_ops(float* tile, const float* sm, int tid){
    constexpr int A_PA[5] = {0,10,8,6,4}, A_PB[5] = {10,8,6,4,2};
    constexpr int B_PA[5] = {2,10,8,6,4}, B_PB[5] = {10,8,6,4,0};
#pragma unroll
    for (int i=0; i<5; i++){
        const int pa = ISB ? B_PA[i] : A_PA[i];
        const int pb = ISB ? B_PB[i] : A_PB[i];
        const int mA = (!ISB && i==0) ? LAYER*160 : -1;               // rot(l,0) on control
        const int mB = !ISB ? (LAYER*10 + i + 1)*16
                            : ((i < 4) ? (LAYER*10 + 6 + i)*16 : -1); // rot(l,6..9)
        const int lo = pa < pb ? pa : pb, hi = pa < pb ? pb : pa;
        unsigned g8 = (unsigned)tid;
        unsigned xx = ((g8 >> lo) << (lo+2)) | (g8 & ((1u<<lo)-1u));
        xx = ((xx >> hi) << (hi+2)) | (xx & ((1u<<hi)-1u));
        unsigned adr[16];
        float v[16];
#pragma unroll
        for (int d=0; d<16; d++){
            unsigned t = xx | ((unsigned)(d>>2) << pa) | ((unsigned)(d&3) << pb);
            adr[d] = swz(t);
            v[d] = tile[adr[d]];
        }
        if (mA >= 0){ const float* M = sm + mA; ALONG_A(M); }
        if (mB >= 0){ const float* M = sm + mB; ALONG_B(M); }
        { // CNOT Pauli-basis signed permutation
            float t0;
            t0=v[4];  v[4]=v[5];   v[5]=t0;
            t0=v[8];  v[8]=v[9];   v[9]=t0;
            t0=v[2];  v[2]=v[14];  v[14]=t0;
            t0=v[3];  v[3]=v[15];  v[15]=t0;
            t0=v[6];  v[6]=v[11];  v[11]=t0;
            t0=v[7];  v[7]=-v[10]; v[10]=-t0;
        }
        { const float* M = sm + 480; ALONG_B(M); ALONG_A(M); }   // N2 target, N2 control
#pragma unroll
        for (int d=0; d<16; d++) tile[adr[d]] = v[d];
        __syncthreads();
    }
}

// ================= sim phase kernel (Pauli rep, fully specialized) =================
// Phase A (ISB=0): tile = bits 0..11 (qubits 0,5,4,3,2,1); block -> bits 12..19.
// Phase B (ISB=1): tile = bits 0..3 + 12..19 (qubits 0,5,9,8,7,6); block -> bits 4..11.
// DOINIT also: compute sm (trig) and have block 0 cache it to smg.
// MODE 3 (P4 = last A phase): store only u=0..15 per block (all that P5's single
//   window reads) + block 0 directly writes the 8 pass-through observables
//   (qubits 1..4: PTM rows for all-I window strings are identity).
template<int LAYER, int ISB, int DOINIT, int MODE>
__global__ void __launch_bounds__(256)
fused6(float* __restrict__ rho, const float* __restrict__ wts,
       float* __restrict__ smg, float* __restrict__ cvec)
{
    __shared__ __align__(16) float tile[4096];
    __shared__ __align__(16) float sm[496];
    int tid = threadIdx.x;
    unsigned blk = blockIdx.x;

    if (DOINIT){
        prep_compute(sm, wts, tid);            // wave 0 only
    } else {
        if (tid < 124)
            reinterpret_cast<float4*>(sm)[tid] = reinterpret_cast<const float4*>(smg)[tid];
    }

    unsigned bo = blk << (ISB ? 4 : 12);
    if (DOINIT){
        // c_s = 1 for s in {I,Z}^10 (digit bits equal), else 0
#pragma unroll
        for (int r=0; r<16; r++){
            unsigned u = tid + 256u*r;
            unsigned g = u | bo;
            unsigned e = g & 0x55555u, o = (g>>1) & 0x55555u;
            tile[swz(u)] = (e==o) ? 1.f : 0.f;
        }
    } else {
#pragma unroll
        for (int r=0; r<4; r++){
            unsigned u = 4u*(tid + 256u*r);
            unsigned g = ISB ? ((u & 15u) | ((u>>4)<<12) | bo) : (u | bo);
            *reinterpret_cast<float4*>(&tile[swz(u)]) = *reinterpret_cast<const float4*>(rho + g);
        }
    }
    __syncthreads();

    if (DOINIT && blk == 0 && tid < 124)       // cache sm for later kernels
        reinterpret_cast<float4*>(smg)[tid] = *reinterpret_cast<const float4*>(&sm[4*tid]);

    run_ops<LAYER, ISB>(tile, sm, tid);

    if (MODE == 3){
        // P5's window blk=0 needs only tile entries u=0..15 of every P4 block
        if (tid < 4)
            *reinterpret_cast<float4*>(rho + (4u*tid | bo)) =
                *reinterpret_cast<const float4*>(&tile[4u*tid]);   // swz identity for u<128
        if (blk == 0 && tid < 8){
            // pass-through observables on qubits 1..4 (cvec[2..9] = X1,Z1,X2,Z2,X3,Z3,X4,Z4)
            const unsigned TI[8] = {1024u,3072u,256u,768u,64u,192u,16u,48u};
            cvec[2 + tid] = tile[swz(TI[tid])];
        }
        return;
    }

#pragma unroll
    for (int r=0; r<4; r++){
        unsigned u = 4u*(tid + 256u*r);
        unsigned g = ISB ? ((u & 15u) | ((u>>4)<<12) | bo) : (u | bo);
        *reinterpret_cast<float4*>(rho + g) = *reinterpret_cast<const float4*>(&tile[swz(u)]);
    }
}

// ================= mega logits: redundant P5 window (no sync) + feats + combine =================
// Each of 256 blocks: (a) rebuild P5's single op-window from P4's sparse output
// (16 KB, L2-broadcast), (b) run the 5 remaining ops, (c) extract the 12 window
// observables locally + read the 8 pass-through ones from cvec, (d) 8 batches of
// Pauli feats + combine + sigmoid. Pure stream-order dependencies, zero atomics.
__global__ void __launch_bounds__(256)
logits_mega(const float* __restrict__ rho, const float* __restrict__ smg,
            const float* __restrict__ cvec,
            const float* __restrict__ x, const float* __restrict__ bvec,
            const float* __restrict__ w, float* __restrict__ out)
{
    __shared__ __align__(16) float tile[4096];
    __shared__ __align__(16) float sm[496];
    __shared__ float cvw[20];
    __shared__ float redl[80];
    int tid = threadIdx.x;
    unsigned bid = blockIdx.x;

    if (tid < 124)
        reinterpret_cast<float4*>(sm)[tid] = reinterpret_cast<const float4*>(smg)[tid];

    // load P5's window: u = lo | hi*16  ->  global g = lo | hi<<12
#pragma unroll
    for (int r=0; r<4; r++){
        unsigned u = 4u*(tid + 256u*r);
        unsigned g = (u & 15u) | ((u>>4)<<12);
        *reinterpret_cast<float4*>(&tile[swz(u)]) = *reinterpret_cast<const float4*>(rho + g);
    }
    __syncthreads();

    run_ops<2, 1>(tile, sm, tid);   // L3 e56..e90 + rots 6..9 (ends with barrier)

    // window observables (tile slot i -> qubit {0,5,9,8,7,6}), + pass-through from cvec
    if (tid < 12){
        const int TQ[6] = {0,5,9,8,7,6};
        int i = tid >> 1, isZ = tid & 1;
        unsigned u = (isZ ? 3u : 1u) << (2*i);
        cvw[2*TQ[i] + isZ] = tile[swz(u)];
    } else if (tid < 20){
        cvw[tid - 10] = cvec[tid - 10];          // cvec[2..9]
    }
    __syncthreads();
    if (tid < 20){
        float s = (tid & 1) ? 0.96f : 1.0f;      // readout bitflip folded into Z
        cvw[tid] = w[tid] * s * cvw[tid];
    }

    // ---- 8 batches of feats + combine; reuse tile[0..1023] as xs ----
    float* xs = tile;
    float4 bv = reinterpret_cast<const float4*>(bvec)[tid];
    for (int k=0; k<8; k++){
        int b = (int)bid*8 + k;
        float4 xv = reinterpret_cast<const float4*>(x + (size_t)b*1024)[tid];
        __syncthreads();                          // prior readers of xs/redl/tile done
        xs[tid*4+0] = xv.x + bv.x;
        xs[tid*4+1] = xv.y + bv.y;
        xs[tid*4+2] = xv.z + bv.z;
        xs[tid*4+3] = xv.w + bv.w;
        __syncthreads();
        float aX[10] = {0,0,0,0,0,0,0,0,0,0};
        float aZ[10] = {0,0,0,0,0,0,0,0,0,0};
#pragma unroll
        for (int r=0; r<4; r++){
            int m = tid + r*256;
            float xm = xs[m];
            float x2 = xm*xm;
#pragma unroll
            for (int q=0; q<10; q++){
                int bit = 1 << (9-q);
                aX[q] += xm * xs[m ^ bit];
                aZ[q] += (m & bit) ? -x2 : x2;
            }
        }
        int lane = tid & 63, wv = tid >> 6;
#pragma unroll
        for (int kk=0; kk<20; kk++){
            float v = (kk < 10) ? aX[kk] : aZ[kk-10];
            v += __shfl_down(v, 32); v += __shfl_down(v, 16); v += __shfl_down(v, 8);
            v += __shfl_down(v, 4);  v += __shfl_down(v, 2);  v += __shfl_down(v, 1);
            if (lane == 0) redl[wv*20 + kk] = v;
        }
        __syncthreads();
        if (tid == 0){
            float logit = 0.f;
#pragma unroll
            for (int q=0; q<10; q++){
                float FX = redl[q]    + redl[20+q] + redl[40+q] + redl[60+q];
                float FZ = redl[10+q] + redl[30+q] + redl[50+q] + redl[70+q];
                logit += cvw[2*q] * FX + cvw[2*q+1] * FZ;
            }
            out[b] = 1.f / (1.f + expf(-logit));
        }
    }
}

// ================= launch =================
extern "C" void kernel_launch(void* const* d_in, const int* in_sizes, int n_in,
                              void* d_out, int out_size, void* d_ws, size_t ws_size,
                              hipStream_t stream) {
    const float* x    = (const float*)d_in[0];   // [2048,1024]
    const float* bvec = (const float*)d_in[1];   // [1024]
    const float* w    = (const float*)d_in[2];   // [20]
    const float* cw   = (const float*)d_in[3];   // [3,10,3]
    float* out = (float*)d_out;

    char* ws = (char*)d_ws;
    float* rho  = (float*)ws;                                       // 2^20 floats = 4 MB
    float* smg  = (float*)(ws + (size_t)(1u<<20)*sizeof(float));    // 496 floats (PTM cache)
    float* cvec = smg + 512;                                        // 20 floats
    (void)ws_size; (void)in_sizes; (void)n_in; (void)out_size;

    fused6<0,0,1,0><<<256, 256, 0, stream>>>(rho, cw, smg, cvec);   // P0: init + L1 first half
    fused6<0,1,0,0><<<256, 256, 0, stream>>>(rho, cw, smg, cvec);   // P1: L1 second half
    fused6<1,0,0,0><<<256, 256, 0, stream>>>(rho, cw, smg, cvec);   // P2: L2 first half
    fused6<1,1,0,0><<<256, 256, 0, stream>>>(rho, cw, smg, cvec);   // P3: L2 second half
    fused6<2,0,0,3><<<256, 256, 0, stream>>>(rho, cw, smg, cvec);   // P4: L3 first half + sparse out
    logits_mega<<<256, 256, 0, stream>>>(rho, smg, cvec, x, bvec, w, out);
}

// Round 12
// 83.690 us; speedup vs baseline: 1.9268x; 1.1423x over previous
//
#include <hip/hip_runtime.h>
#include <hip/hip_bf16.h>
#include <math.h>

// ================= complex 2x2 helpers (prep only) =================
struct cf { float x, y; };
__device__ __forceinline__ cf cfmul(cf a, cf b){ return {a.x*b.x - a.y*b.y, a.x*b.y + a.y*b.x}; }
__device__ __forceinline__ cf cfconj(cf a){ return {a.x, -a.y}; }
__device__ __forceinline__ cf cfadd(cf a, cf b){ return {a.x+b.x, a.y+b.y}; }

__device__ __forceinline__ void pmat(int k, cf* P){
    if (k==0){ P[0]={1.f,0.f}; P[1]={0.f,0.f}; P[2]={0.f,0.f}; P[3]={1.f,0.f}; }
    else if (k==1){ P[0]={0.f,0.f}; P[1]={1.f,0.f}; P[2]={1.f,0.f}; P[3]={0.f,0.f}; }
    else if (k==2){ P[0]={0.f,0.f}; P[1]={0.f,-1.f}; P[2]={0.f,1.f}; P[3]={0.f,0.f}; }
    else { P[0]={1.f,0.f}; P[1]={0.f,0.f}; P[2]={0.f,0.f}; P[3]={-1.f,0.f}; }
}
__device__ void mul2(cf* C, const cf* A, const cf* B){
    C[0]=cfadd(cfmul(A[0],B[0]),cfmul(A[1],B[2]));
    C[1]=cfadd(cfmul(A[0],B[1]),cfmul(A[1],B[3]));
    C[2]=cfadd(cfmul(A[2],B[0]),cfmul(A[3],B[2]));
    C[3]=cfadd(cfmul(A[2],B[1]),cfmul(A[3],B[3]));
}
// T[t*4+s] += 0.5 * Re tr(P_t K P_s K^dagger)
__device__ void ptm_acc(float* T, const cf* K){
    cf Kd[4] = {cfconj(K[0]), cfconj(K[2]), cfconj(K[1]), cfconj(K[3])};
    for (int s=0;s<4;s++){
        cf Ps[4]; pmat(s,Ps);
        cf t1[4], t2[4];
        mul2(t1, K, Ps);
        mul2(t2, t1, Kd);
        for (int t=0;t<4;t++){
            cf Pt[4]; pmat(t,Pt);
            float re = Pt[0].x*t2[0].x - Pt[0].y*t2[0].y
                     + Pt[1].x*t2[2].x - Pt[1].y*t2[2].y
                     + Pt[2].x*t2[1].x - Pt[2].y*t2[1].y
                     + Pt[3].x*t2[3].x - Pt[3].y*t2[3].y;
            T[t*4+s] += 0.5f*re;
        }
    }
}
__device__ void rmm4(float* C, const float* A, const float* B){
    for (int i=0;i<4;i++) for (int j=0;j<4;j++){
        float s=0.f;
        for (int k=0;k<4;k++) s += A[i*4+k]*B[k*4+j];
        C[i*4+j]=s;
    }
}

// prep compute: threads 0..30 fill sm[0..495] with REAL Pauli-transfer mats.
// sm[(l*10+q)*16..] = Tnoise1 * Trot(l,q); sm[480..] = Tnoise2 (N2).
__device__ void prep_compute(float* sm, const float* __restrict__ wts, int tid){
    if (tid < 31){
        const float GA = -expm1f(-2.0000000000000002e-06f);   // 1-exp(-GATE/T1)
        const float GP = -expm1f(-1.4285714285714286e-06f);   // 1-exp(-GATE/T2)
        float sa = sqrtf(1.f-GA), spp = sqrtf(1.f-GP);
        float p = (tid==30) ? 0.01f : 0.001f;
        float f = 1.f - (4.f/3.f)*p;
        float Tn[16] = {0};
        Tn[0]      = 1.f;
        Tn[1*4+1]  = spp*sa*f;
        Tn[2*4+2]  = spp*sa*f;
        Tn[3*4+3]  = (1.f-GA)*f;
        Tn[3*4+0]  = GA;
        if (tid == 30){
            for (int i=0;i<16;i++) sm[480+i] = Tn[i];
        } else {
            float phi = wts[tid*3+0], th = wts[tid*3+1], om = wts[tid*3+2];
            float ct = cosf(0.5f*th), st = sinf(0.5f*th);
            cf ep = {cosf(0.5f*(phi+om)), -sinf(0.5f*(phi+om))};
            cf em = {cosf(0.5f*(phi-om)),  sinf(0.5f*(phi-om))};
            cf U[4];
            U[0] = { ep.x*ct,  ep.y*ct};
            U[1] = {-em.x*st, -em.y*st};
            U[2] = { em.x*st, -em.y*st};
            U[3] = { ep.x*ct, -ep.y*ct};
            float Tr[16] = {0};
            ptm_acc(Tr, U);                 // unitary: single Kraus
            float S[16]; rmm4(S, Tn, Tr);   // rot first, then noise
            for (int i=0;i<16;i++) sm[tid*16+i] = S[i];
        }
    }
}

// LDS swizzle on 12-bit float index: XOR bits 9..11 into 2..4 (float4-preserving)
__device__ __forceinline__ unsigned swz(unsigned t){ return t ^ ((t>>7)&0x1Cu); }

#define ALONG_A(Mp) { _Pragma("unroll") for (int db_=0; db_<4; db_++){ \
    float a0=v[db_], a1=v[4+db_], a2=v[8+db_], a3=v[12+db_]; \
    _Pragma("unroll") for (int dp_=0; dp_<4; dp_++){ \
        v[dp_*4+db_] = (Mp)[dp_*4+0]*a0 + (Mp)[dp_*4+1]*a1 + (Mp)[dp_*4+2]*a2 + (Mp)[dp_*4+3]*a3; } } }

#define ALONG_B(Mp) { _Pragma("unroll") for (int da_=0; da_<4; da_++){ \
    float a0=v[da_*4+0], a1=v[da_*4+1], a2=v[da_*4+2], a3=v[da_*4+3]; \
    _Pragma("unroll") for (int dp_=0; dp_<4; dp_++){ \
        v[da_*4+dp_] = (Mp)[dp_*4+0]*a0 + (Mp)[dp_*4+1]*a1 + (Mp)[dp_*4+2]*a2 + (Mp)[dp_*4+3]*a3; } } }

// shared op-chain (5 ops of one phase window). ISB selects bit tables; LAYER selects mats.
template<int LAYER, int ISB>
__device__ __forceinline__ void run_ops(float* tile, const float* sm, int tid){
    constexpr int A_PA[5] = {0,10,8,6,4}, A_PB[5] = {10,8,6,4,2};
    constexpr int B_PA[5] = {2,10,8,6,4}, B_PB[5] = {10,8,6,4,0};
#pragma unroll
    for (int i=0; i<5; i++){
        const int pa = ISB ? B_PA[i] : A_PA[i];
        const int pb = ISB ? B_PB[i] : A_PB[i];
        const int mA = (!ISB && i==0) ? LAYER*160 : -1;               // rot(l,0) on control
        const int mB = !ISB ? (LAYER*10 + i + 1)*16
                            : ((i < 4) ? (LAYER*10 + 6 + i)*16 : -1); // rot(l,6..9)
        const int lo = pa < pb ? pa : pb, hi = pa < pb ? pb : pa;
        unsigned g8 = (unsigned)tid;
        unsigned xx = ((g8 >> lo) << (lo+2)) | (g8 & ((1u<<lo)-1u));
        xx = ((xx >> hi) << (hi+2)) | (xx & ((1u<<hi)-1u));
        unsigned adr[16];
        float v[16];
#pragma unroll
        for (int d=0; d<16; d++){
            unsigned t = xx | ((unsigned)(d>>2) << pa) | ((unsigned)(d&3) << pb);
            adr[d] = swz(t);
            v[d] = tile[adr[d]];
        }
        if (mA >= 0){ const float* M = sm + mA; ALONG_A(M); }
        if (mB >= 0){ const float* M = sm + mB; ALONG_B(M); }
        { // CNOT Pauli-basis signed permutation
            float t0;
            t0=v[4];  v[4]=v[5];   v[5]=t0;
            t0=v[8];  v[8]=v[9];   v[9]=t0;
            t0=v[2];  v[2]=v[14];  v[14]=t0;
            t0=v[3];  v[3]=v[15];  v[15]=t0;
            t0=v[6];  v[6]=v[11];  v[11]=t0;
            t0=v[7];  v[7]=-v[10]; v[10]=-t0;
        }
        { const float* M = sm + 480; ALONG_B(M); ALONG_A(M); }   // N2 target, N2 control
#pragma unroll
        for (int d=0; d<16; d++) tile[adr[d]] = v[d];
        __syncthreads();
    }
}

// ================= sim phase kernel (Pauli rep, fully specialized) =================
// Phase A (ISB=0): tile = bits 0..11 (qubits 0,5,4,3,2,1); block -> bits 12..19.
// Phase B (ISB=1): tile = bits 0..3 + 12..19 (qubits 0,5,9,8,7,6); block -> bits 4..11.
// DOINIT also: compute sm (trig) and have block 0 cache it to smg.
// MODE 3 (P4 = last A phase): store only u=0..15 per block (all that P5's single
//   window reads) + block 0 directly writes the 8 pass-through observables
//   (qubits 1..4: PTM rows for all-I window strings are identity).
template<int LAYER, int ISB, int DOINIT, int MODE>
__global__ void __launch_bounds__(256)
fused6(float* __restrict__ rho, const float* __restrict__ wts,
       float* __restrict__ smg, float* __restrict__ cvec)
{
    __shared__ __align__(16) float tile[4096];
    __shared__ __align__(16) float sm[496];
    int tid = threadIdx.x;
    unsigned blk = blockIdx.x;

    if (DOINIT){
        prep_compute(sm, wts, tid);            // wave 0 only
    } else {
        if (tid < 124)
            reinterpret_cast<float4*>(sm)[tid] = reinterpret_cast<const float4*>(smg)[tid];
    }

    unsigned bo = blk << (ISB ? 4 : 12);
    if (DOINIT){
        // c_s = 1 for s in {I,Z}^10 (digit bits equal), else 0
#pragma unroll
        for (int r=0; r<16; r++){
            unsigned u = tid + 256u*r;
            unsigned g = u | bo;
            unsigned e = g & 0x55555u, o = (g>>1) & 0x55555u;
            tile[swz(u)] = (e==o) ? 1.f : 0.f;
        }
    } else {
#pragma unroll
        for (int r=0; r<4; r++){
            unsigned u = 4u*(tid + 256u*r);
            unsigned g = ISB ? ((u & 15u) | ((u>>4)<<12) | bo) : (u | bo);
            *reinterpret_cast<float4*>(&tile[swz(u)]) = *reinterpret_cast<const float4*>(rho + g);
        }
    }
    __syncthreads();

    if (DOINIT && blk == 0 && tid < 124)       // cache sm for later kernels
        reinterpret_cast<float4*>(smg)[tid] = *reinterpret_cast<const float4*>(&sm[4*tid]);

    run_ops<LAYER, ISB>(tile, sm, tid);

    if (MODE == 3){
        // P5's window blk=0 needs only tile entries u=0..15 of every P4 block
        if (tid < 4)
            *reinterpret_cast<float4*>(rho + (4u*tid | bo)) =
                *reinterpret_cast<const float4*>(&tile[4u*tid]);   // swz identity for u<128
        if (blk == 0 && tid < 8){
            // pass-through observables on qubits 1..4 (cvec[2..9] = X1,Z1,X2,Z2,X3,Z3,X4,Z4)
            const unsigned TI[8] = {1024u,3072u,256u,768u,64u,192u,16u,48u};
            cvec[2 + tid] = tile[swz(TI[tid])];
        }
        return;
    }

#pragma unroll
    for (int r=0; r<4; r++){
        unsigned u = 4u*(tid + 256u*r);
        unsigned g = ISB ? ((u & 15u) | ((u>>4)<<12) | bo) : (u | bo);
        *reinterpret_cast<float4*>(rho + g) = *reinterpret_cast<const float4*>(&tile[swz(u)]);
    }
}

// ================= logits (grid 2048, 1 batch/block): redundant P5 window + feats =================
// Each block: (a) rebuild P5's single op-window from P4's sparse output (16 KB,
// L2-broadcast), (b) run the 5 remaining ops, (c) extract the 12 window observables
// locally + read the 8 pass-through ones from cvec, (d) its batch's Pauli feats +
// combine + sigmoid. Pure stream-order dependencies, zero atomics, zero spins.
__global__ void __launch_bounds__(256)
logits_mega(const float* __restrict__ rho, const float* __restrict__ smg,
            const float* __restrict__ cvec,
            const float* __restrict__ x, const float* __restrict__ bvec,
            const float* __restrict__ w, float* __restrict__ out)
{
    __shared__ __align__(16) float tile[4096];
    __shared__ __align__(16) float sm[496];
    __shared__ float cvw[20];
    __shared__ float redl[80];
    int tid = threadIdx.x;
    int b = (int)blockIdx.x;

    if (tid < 124)
        reinterpret_cast<float4*>(sm)[tid] = reinterpret_cast<const float4*>(smg)[tid];

    // load P5's window: u = lo | hi*16  ->  global g = lo | hi<<12
#pragma unroll
    for (int r=0; r<4; r++){
        unsigned u = 4u*(tid + 256u*r);
        unsigned g = (u & 15u) | ((u>>4)<<12);
        *reinterpret_cast<float4*>(&tile[swz(u)]) = *reinterpret_cast<const float4*>(rho + g);
    }
    __syncthreads();

    run_ops<2, 1>(tile, sm, tid);   // L3 e56..e90 + rots 6..9 (ends with barrier)

    // window observables (tile slot i -> qubit {0,5,9,8,7,6}), + pass-through from cvec
    if (tid < 12){
        const int TQ[6] = {0,5,9,8,7,6};
        int i = tid >> 1, isZ = tid & 1;
        unsigned u = (isZ ? 3u : 1u) << (2*i);
        cvw[2*TQ[i] + isZ] = tile[swz(u)];
    } else if (tid < 20){
        cvw[tid - 10] = cvec[tid - 10];          // cvec[2..9]
    }
    __syncthreads();                              // cvw written; tile obs reads done
    if (tid < 20){
        float s = (tid & 1) ? 0.96f : 1.0f;      // readout bitflip folded into Z
        cvw[tid] = w[tid] * s * cvw[tid];
    }

    // ---- feats for batch b; reuse tile[0..1023] as xs ----
    float* xs = tile;
    {
        float4 xv = reinterpret_cast<const float4*>(x + (size_t)b*1024)[tid];
        float4 bv = reinterpret_cast<const float4*>(bvec)[tid];
        xs[tid*4+0] = xv.x + bv.x;
        xs[tid*4+1] = xv.y + bv.y;
        xs[tid*4+2] = xv.z + bv.z;
        xs[tid*4+3] = xv.w + bv.w;
    }
    __syncthreads();
    float aX[10] = {0,0,0,0,0,0,0,0,0,0};
    float aZ[10] = {0,0,0,0,0,0,0,0,0,0};
#pragma unroll
    for (int r=0; r<4; r++){
        int m = tid + r*256;
        float xm = xs[m];
        float x2 = xm*xm;
#pragma unroll
        for (int q=0; q<10; q++){
            int bit = 1 << (9-q);
            aX[q] += xm * xs[m ^ bit];
            aZ[q] += (m & bit) ? -x2 : x2;
        }
    }
    int lane = tid & 63, wv = tid >> 6;
#pragma unroll
    for (int kk=0; kk<20; kk++){
        float v = (kk < 10) ? aX[kk] : aZ[kk-10];
        v += __shfl_down(v, 32); v += __shfl_down(v, 16); v += __shfl_down(v, 8);
        v += __shfl_down(v, 4);  v += __shfl_down(v, 2);  v += __shfl_down(v, 1);
        if (lane == 0) redl[wv*20 + kk] = v;
    }
    __syncthreads();
    if (tid == 0){
        float logit = 0.f;
#pragma unroll
        for (int q=0; q<10; q++){
            float FX = redl[q]    + redl[20+q] + redl[40+q] + redl[60+q];
            float FZ = redl[10+q] + redl[30+q] + redl[50+q] + redl[70+q];
            logit += cvw[2*q] * FX + cvw[2*q+1] * FZ;
        }
        out[b] = 1.f / (1.f + expf(-logit));
    }
}

// ================= launch =================
extern "C" void kernel_launch(void* const* d_in, const int* in_sizes, int n_in,
                              void* d_out, int out_size, void* d_ws, size_t ws_size,
                              hipStream_t stream) {
    const float* x    = (const float*)d_in[0];   // [2048,1024]
    const float* bvec = (const float*)d_in[1];   // [1024]
    const float* w    = (const float*)d_in[2];   // [20]
    const float* cw   = (const float*)d_in[3];   // [3,10,3]
    float* out = (float*)d_out;

    char* ws = (char*)d_ws;
    float* rho  = (float*)ws;                                       // 2^20 floats = 4 MB
    float* smg  = (float*)(ws + (size_t)(1u<<20)*sizeof(float));    // 496 floats (PTM cache)
    float* cvec = smg + 512;                                        // 20 floats
    (void)ws_size; (void)in_sizes; (void)n_in; (void)out_size;

    fused6<0,0,1,0><<<256, 256, 0, stream>>>(rho, cw, smg, cvec);   // P0: init + L1 first half
    fused6<0,1,0,0><<<256, 256, 0, stream>>>(rho, cw, smg, cvec);   // P1: L1 second half
    fused6<1,0,0,0><<<256, 256, 0, stream>>>(rho, cw, smg, cvec);   // P2: L2 first half
    fused6<1,1,0,0><<<256, 256, 0, stream>>>(rho, cw, smg, cvec);   // P3: L2 second half
    fused6<2,0,0,3><<<256, 256, 0, stream>>>(rho, cw, smg, cvec);   // P4: L3 first half + sparse out
    logits_mega<<<2048, 256, 0, stream>>>(rho, smg, cvec, x, bvec, w, out);
}

// Round 13
// 83.601 us; speedup vs baseline: 1.9288x; 1.0011x over previous
//
#include <hip/hip_runtime.h>
#include <hip/hip_bf16.h>
#include <math.h>

// ================= complex 2x2 helpers (prep only) =================
struct cf { float x, y; };
__device__ __forceinline__ cf cfmul(cf a, cf b){ return {a.x*b.x - a.y*b.y, a.x*b.y + a.y*b.x}; }
__device__ __forceinline__ cf cfconj(cf a){ return {a.x, -a.y}; }
__device__ __forceinline__ cf cfadd(cf a, cf b){ return {a.x+b.x, a.y+b.y}; }

__device__ __forceinline__ void pmat(int k, cf* P){
    if (k==0){ P[0]={1.f,0.f}; P[1]={0.f,0.f}; P[2]={0.f,0.f}; P[3]={1.f,0.f}; }
    else if (k==1){ P[0]={0.f,0.f}; P[1]={1.f,0.f}; P[2]={1.f,0.f}; P[3]={0.f,0.f}; }
    else if (k==2){ P[0]={0.f,0.f}; P[1]={0.f,-1.f}; P[2]={0.f,1.f}; P[3]={0.f,0.f}; }
    else { P[0]={1.f,0.f}; P[1]={0.f,0.f}; P[2]={0.f,0.f}; P[3]={-1.f,0.f}; }
}
__device__ void mul2(cf* C, const cf* A, const cf* B){
    C[0]=cfadd(cfmul(A[0],B[0]),cfmul(A[1],B[2]));
    C[1]=cfadd(cfmul(A[0],B[1]),cfmul(A[1],B[3]));
    C[2]=cfadd(cfmul(A[2],B[0]),cfmul(A[3],B[2]));
    C[3]=cfadd(cfmul(A[2],B[1]),cfmul(A[3],B[3]));
}
// T[t*4+s] += 0.5 * Re tr(P_t K P_s K^dagger)
__device__ void ptm_acc(float* T, const cf* K){
    cf Kd[4] = {cfconj(K[0]), cfconj(K[2]), cfconj(K[1]), cfconj(K[3])};
    for (int s=0;s<4;s++){
        cf Ps[4]; pmat(s,Ps);
        cf t1[4], t2[4];
        mul2(t1, K, Ps);
        mul2(t2, t1, Kd);
        for (int t=0;t<4;t++){
            cf Pt[4]; pmat(t,Pt);
            float re = Pt[0].x*t2[0].x - Pt[0].y*t2[0].y
                     + Pt[1].x*t2[2].x - Pt[1].y*t2[2].y
                     + Pt[2].x*t2[1].x - Pt[2].y*t2[1].y
                     + Pt[3].x*t2[3].x - Pt[3].y*t2[3].y;
            T[t*4+s] += 0.5f*re;
        }
    }
}
__device__ void rmm4(float* C, const float* A, const float* B){
    for (int i=0;i<4;i++) for (int j=0;j<4;j++){
        float s=0.f;
        for (int k=0;k<4;k++) s += A[i*4+k]*B[k*4+j];
        C[i*4+j]=s;
    }
}

// prep compute: threads 0..30 fill sm[0..495] with REAL Pauli-transfer mats.
// sm[(l*10+q)*16..] = Tnoise1 * Trot(l,q); sm[480..] = Tnoise2 (N2).
__device__ void prep_compute(float* sm, const float* __restrict__ wts, int tid){
    if (tid < 31){
        const float GA = -expm1f(-2.0000000000000002e-06f);   // 1-exp(-GATE/T1)
        const float GP = -expm1f(-1.4285714285714286e-06f);   // 1-exp(-GATE/T2)
        float sa = sqrtf(1.f-GA), spp = sqrtf(1.f-GP);
        float p = (tid==30) ? 0.01f : 0.001f;
        float f = 1.f - (4.f/3.f)*p;
        float Tn[16] = {0};
        Tn[0]      = 1.f;
        Tn[1*4+1]  = spp*sa*f;
        Tn[2*4+2]  = spp*sa*f;
        Tn[3*4+3]  = (1.f-GA)*f;
        Tn[3*4+0]  = GA;
        if (tid == 30){
            for (int i=0;i<16;i++) sm[480+i] = Tn[i];
        } else {
            float phi = wts[tid*3+0], th = wts[tid*3+1], om = wts[tid*3+2];
            float ct = cosf(0.5f*th), st = sinf(0.5f*th);
            cf ep = {cosf(0.5f*(phi+om)), -sinf(0.5f*(phi+om))};
            cf em = {cosf(0.5f*(phi-om)),  sinf(0.5f*(phi-om))};
            cf U[4];
            U[0] = { ep.x*ct,  ep.y*ct};
            U[1] = {-em.x*st, -em.y*st};
            U[2] = { em.x*st, -em.y*st};
            U[3] = { ep.x*ct, -ep.y*ct};
            float Tr[16] = {0};
            ptm_acc(Tr, U);                 // unitary: single Kraus
            float S[16]; rmm4(S, Tn, Tr);   // rot first, then noise
            for (int i=0;i<16;i++) sm[tid*16+i] = S[i];
        }
    }
}

// LDS swizzle on 12-bit float index: XOR bits 9..11 into 2..4 (float4-preserving)
__device__ __forceinline__ unsigned swz(unsigned t){ return t ^ ((t>>7)&0x1Cu); }

#define ALONG_A(Mp) { _Pragma("unroll") for (int db_=0; db_<4; db_++){ \
    float a0=v[db_], a1=v[4+db_], a2=v[8+db_], a3=v[12+db_]; \
    _Pragma("unroll") for (int dp_=0; dp_<4; dp_++){ \
        v[dp_*4+db_] = (Mp)[dp_*4+0]*a0 + (Mp)[dp_*4+1]*a1 + (Mp)[dp_*4+2]*a2 + (Mp)[dp_*4+3]*a3; } } }

#define ALONG_B(Mp) { _Pragma("unroll") for (int da_=0; da_<4; da_++){ \
    float a0=v[da_*4+0], a1=v[da_*4+1], a2=v[da_*4+2], a3=v[da_*4+3]; \
    _Pragma("unroll") for (int dp_=0; dp_<4; dp_++){ \
        v[da_*4+dp_] = (Mp)[dp_*4+0]*a0 + (Mp)[dp_*4+1]*a1 + (Mp)[dp_*4+2]*a2 + (Mp)[dp_*4+3]*a3; } } }

// shared op-chain (5 ops of one phase window). ISB selects bit tables; LAYER selects mats.
template<int LAYER, int ISB>
__device__ __forceinline__ void run_ops(float* tile, const float* sm, int tid){
    constexpr int A_PA[5] = {0,10,8,6,4}, A_PB[5] = {10,8,6,4,2};
    constexpr int B_PA[5] = {2,10,8,6,4}, B_PB[5] = {10,8,6,4,0};
#pragma unroll
    for (int i=0; i<5; i++){
        const int pa = ISB ? B_PA[i] : A_PA[i];
        const int pb = ISB ? B_PB[i] : A_PB[i];
        const int mA = (!ISB && i==0) ? LAYER*160 : -1;               // rot(l,0) on control
        const int mB = !ISB ? (LAYER*10 + i + 1)*16
                            : ((i < 4) ? (LAYER*10 + 6 + i)*16 : -1); // rot(l,6..9)
        const int lo = pa < pb ? pa : pb, hi = pa < pb ? pb : pa;
        unsigned g8 = (unsigned)tid;
        unsigned xx = ((g8 >> lo) << (lo+2)) | (g8 & ((1u<<lo)-1u));
        xx = ((xx >> hi) << (hi+2)) | (xx & ((1u<<hi)-1u));
        unsigned adr[16];
        float v[16];
#pragma unroll
        for (int d=0; d<16; d++){
            unsigned t = xx | ((unsigned)(d>>2) << pa) | ((unsigned)(d&3) << pb);
            adr[d] = swz(t);
            v[d] = tile[adr[d]];
        }
        if (mA >= 0){ const float* M = sm + mA; ALONG_A(M); }
        if (mB >= 0){ const float* M = sm + mB; ALONG_B(M); }
        { // CNOT Pauli-basis signed permutation
            float t0;
            t0=v[4];  v[4]=v[5];   v[5]=t0;
            t0=v[8];  v[8]=v[9];   v[9]=t0;
            t0=v[2];  v[2]=v[14];  v[14]=t0;
            t0=v[3];  v[3]=v[15];  v[15]=t0;
            t0=v[6];  v[6]=v[11];  v[11]=t0;
            t0=v[7];  v[7]=-v[10]; v[10]=-t0;
        }
        { const float* M = sm + 480; ALONG_B(M); ALONG_A(M); }   // N2 target, N2 control
#pragma unroll
        for (int d=0; d<16; d++) tile[adr[d]] = v[d];
        __syncthreads();
    }
}

// ================= sim phase kernel (Pauli rep, fully specialized) =================
// Phase A (ISB=0): tile = bits 0..11 (qubits 0,5,4,3,2,1); block -> bits 12..19.
// Phase B (ISB=1): tile = bits 0..3 + 12..19 (qubits 0,5,9,8,7,6); block -> bits 4..11.
// DOINIT also: compute sm (trig) and have block 0 cache it to smg.
// MODE 3 (P4 = last A phase): store only u=0..15 per block (all that P5's single
//   window reads) + block 0 directly writes the 8 pass-through observables
//   (qubits 1..4: PTM rows for all-I window strings are identity).
template<int LAYER, int ISB, int DOINIT, int MODE>
__global__ void __launch_bounds__(256)
fused6(float* __restrict__ rho, const float* __restrict__ wts,
       float* __restrict__ smg, float* __restrict__ cvec)
{
    __shared__ __align__(16) float tile[4096];
    __shared__ __align__(16) float sm[496];
    int tid = threadIdx.x;
    unsigned blk = blockIdx.x;

    if (DOINIT){
        prep_compute(sm, wts, tid);            // wave 0 only
    } else {
        if (tid < 124)
            reinterpret_cast<float4*>(sm)[tid] = reinterpret_cast<const float4*>(smg)[tid];
    }

    unsigned bo = blk << (ISB ? 4 : 12);
    if (DOINIT){
        // c_s = 1 for s in {I,Z}^10 (digit bits equal), else 0
#pragma unroll
        for (int r=0; r<16; r++){
            unsigned u = tid + 256u*r;
            unsigned g = u | bo;
            unsigned e = g & 0x55555u, o = (g>>1) & 0x55555u;
            tile[swz(u)] = (e==o) ? 1.f : 0.f;
        }
    } else {
#pragma unroll
        for (int r=0; r<4; r++){
            unsigned u = 4u*(tid + 256u*r);
            unsigned g = ISB ? ((u & 15u) | ((u>>4)<<12) | bo) : (u | bo);
            *reinterpret_cast<float4*>(&tile[swz(u)]) = *reinterpret_cast<const float4*>(rho + g);
        }
    }
    __syncthreads();

    if (DOINIT && blk == 0 && tid < 124)       // cache sm for later kernels
        reinterpret_cast<float4*>(smg)[tid] = *reinterpret_cast<const float4*>(&sm[4*tid]);

    run_ops<LAYER, ISB>(tile, sm, tid);

    if (MODE == 3){
        // P5's window blk=0 needs only tile entries u=0..15 of every P4 block
        if (tid < 4)
            *reinterpret_cast<float4*>(rho + (4u*tid | bo)) =
                *reinterpret_cast<const float4*>(&tile[4u*tid]);   // swz identity for u<128
        if (blk == 0 && tid < 8){
            // pass-through observables on qubits 1..4 (cvec[2..9] = X1,Z1,X2,Z2,X3,Z3,X4,Z4)
            const unsigned TI[8] = {1024u,3072u,256u,768u,64u,192u,16u,48u};
            cvec[2 + tid] = tile[swz(TI[tid])];
        }
        return;
    }

#pragma unroll
    for (int r=0; r<4; r++){
        unsigned u = 4u*(tid + 256u*r);
        unsigned g = ISB ? ((u & 15u) | ((u>>4)<<12) | bo) : (u | bo);
        *reinterpret_cast<float4*>(rho + g) = *reinterpret_cast<const float4*>(&tile[swz(u)]);
    }
}

// ================= logits (grid 2048, 1 batch/block): redundant P5 window + feats =================
// Each block: (a) rebuild P5's single op-window from P4's sparse output (16 KB,
// L2-broadcast), (b) run the 5 remaining ops, (c) extract the 12 window observables
// locally + read the 8 pass-through ones from cvec, (d) its batch's Pauli feats +
// combine + sigmoid. Pure stream-order dependencies, zero atomics, zero spins.
__global__ void __launch_bounds__(256)
logits_mega(const float* __restrict__ rho, const float* __restrict__ smg,
            const float* __restrict__ cvec,
            const float* __restrict__ x, const float* __restrict__ bvec,
            const float* __restrict__ w, float* __restrict__ out)
{
    __shared__ __align__(16) float tile[4096];
    __shared__ __align__(16) float sm[496];
    __shared__ float cvw[20];
    __shared__ float redl[80];
    int tid = threadIdx.x;
    int b = (int)blockIdx.x;

    if (tid < 124)
        reinterpret_cast<float4*>(sm)[tid] = reinterpret_cast<const float4*>(smg)[tid];

    // load P5's window: u = lo | hi*16  ->  global g = lo | hi<<12
#pragma unroll
    for (int r=0; r<4; r++){
        unsigned u = 4u*(tid + 256u*r);
        unsigned g = (u & 15u) | ((u>>4)<<12);
        *reinterpret_cast<float4*>(&tile[swz(u)]) = *reinterpret_cast<const float4*>(rho + g);
    }
    __syncthreads();

    run_ops<2, 1>(tile, sm, tid);   // L3 e56..e90 + rots 6..9 (ends with barrier)

    // window observables (tile slot i -> qubit {0,5,9,8,7,6}), + pass-through from cvec
    if (tid < 12){
        const int TQ[6] = {0,5,9,8,7,6};
        int i = tid >> 1, isZ = tid & 1;
        unsigned u = (isZ ? 3u : 1u) << (2*i);
        cvw[2*TQ[i] + isZ] = tile[swz(u)];
    } else if (tid < 20){
        cvw[tid - 10] = cvec[tid - 10];          // cvec[2..9]
    }
    __syncthreads();                              // cvw written; tile obs reads done
    if (tid < 20){
        float s = (tid & 1) ? 0.96f : 1.0f;      // readout bitflip folded into Z
        cvw[tid] = w[tid] * s * cvw[tid];
    }

    // ---- feats for batch b; reuse tile[0..1023] as xs ----
    float* xs = tile;
    {
        float4 xv = reinterpret_cast<const float4*>(x + (size_t)b*1024)[tid];
        float4 bv = reinterpret_cast<const float4*>(bvec)[tid];
        xs[tid*4+0] = xv.x + bv.x;
        xs[tid*4+1] = xv.y + bv.y;
        xs[tid*4+2] = xv.z + bv.z;
        xs[tid*4+3] = xv.w + bv.w;
    }
    __syncthreads();
    float aX[10] = {0,0,0,0,0,0,0,0,0,0};
    float aZ[10] = {0,0,0,0,0,0,0,0,0,0};
#pragma unroll
    for (int r=0; r<4; r++){
        int m = tid + r*256;
        float xm = xs[m];
        float x2 = xm*xm;
#pragma unroll
        for (int q=0; q<10; q++){
            int bit = 1 << (9-q);
            aX[q] += xm * xs[m ^ bit];
            aZ[q] += (m & bit) ? -x2 : x2;
        }
    }
    int lane = tid & 63, wv = tid >> 6;
#pragma unroll
    for (int kk=0; kk<20; kk++){
        float v = (kk < 10) ? aX[kk] : aZ[kk-10];
        v += __shfl_down(v, 32); v += __shfl_down(v, 16); v += __shfl_down(v, 8);
        v += __shfl_down(v, 4);  v += __shfl_down(v, 2);  v += __shfl_down(v, 1);
        if (lane == 0) redl[wv*20 + kk] = v;
    }
    __syncthreads();
    if (tid == 0){
        float logit = 0.f;
#pragma unroll
        for (int q=0; q<10; q++){
            float FX = redl[q]    + redl[20+q] + redl[40+q] + redl[60+q];
            float FZ = redl[10+q] + redl[30+q] + redl[50+q] + redl[70+q];
            logit += cvw[2*q] * FX + cvw[2*q+1] * FZ;
        }
        out[b] = 1.f / (1.f + expf(-logit));
    }
}

// ================= launch =================
extern "C" void kernel_launch(void* const* d_in, const int* in_sizes, int n_in,
                              void* d_out, int out_size, void* d_ws, size_t ws_size,
                              hipStream_t stream) {
    const float* x    = (const float*)d_in[0];   // [2048,1024]
    const float* bvec = (const float*)d_in[1];   // [1024]
    const float* w    = (const float*)d_in[2];   // [20]
    const float* cw   = (const float*)d_in[3];   // [3,10,3]
    float* out = (float*)d_out;

    char* ws = (char*)d_ws;
    float* rho  = (float*)ws;                                       // 2^20 floats = 4 MB
    float* smg  = (float*)(ws + (size_t)(1u<<20)*sizeof(float));    // 496 floats (PTM cache)
    float* cvec = smg + 512;                                        // 20 floats
    (void)ws_size; (void)in_sizes; (void)n_in; (void)out_size;

    fused6<0,0,1,0><<<256, 256, 0, stream>>>(rho, cw, smg, cvec);   // P0: init + L1 first half
    fused6<0,1,0,0><<<256, 256, 0, stream>>>(rho, cw, smg, cvec);   // P1: L1 second half
    fused6<1,0,0,0><<<256, 256, 0, stream>>>(rho, cw, smg, cvec);   // P2: L2 first half
    fused6<1,1,0,0><<<256, 256, 0, stream>>>(rho, cw, smg, cvec);   // P3: L2 second half
    fused6<2,0,0,3><<<256, 256, 0, stream>>>(rho, cw, smg, cvec);   // P4: L3 first half + sparse out
    logits_mega<<<2048, 256, 0, stream>>>(rho, smg, cvec, x, bvec, w, out);
}

// Round 14
// 70.251 us; speedup vs baseline: 2.2953x; 1.1900x over previous
//
#include <hip/hip_runtime.h>
#include <hip/hip_bf16.h>
#include <math.h>

// ================= complex 2x2 helpers (prep only) =================
struct cf { float x, y; };
__device__ __forceinline__ cf cfmul(cf a, cf b){ return {a.x*b.x - a.y*b.y, a.x*b.y + a.y*b.x}; }
__device__ __forceinline__ cf cfconj(cf a){ return {a.x, -a.y}; }
__device__ __forceinline__ cf cfadd(cf a, cf b){ return {a.x+b.x, a.y+b.y}; }

__device__ __forceinline__ void pmat(int k, cf* P){
    if (k==0){ P[0]={1.f,0.f}; P[1]={0.f,0.f}; P[2]={0.f,0.f}; P[3]={1.f,0.f}; }
    else if (k==1){ P[0]={0.f,0.f}; P[1]={1.f,0.f}; P[2]={1.f,0.f}; P[3]={0.f,0.f}; }
    else if (k==2){ P[0]={0.f,0.f}; P[1]={0.f,-1.f}; P[2]={0.f,1.f}; P[3]={0.f,0.f}; }
    else { P[0]={1.f,0.f}; P[1]={0.f,0.f}; P[2]={0.f,0.f}; P[3]={-1.f,0.f}; }
}
__device__ void mul2(cf* C, const cf* A, const cf* B){
    C[0]=cfadd(cfmul(A[0],B[0]),cfmul(A[1],B[2]));
    C[1]=cfadd(cfmul(A[0],B[1]),cfmul(A[1],B[3]));
    C[2]=cfadd(cfmul(A[2],B[0]),cfmul(A[3],B[2]));
    C[3]=cfadd(cfmul(A[2],B[1]),cfmul(A[3],B[3]));
}
// T[t*4+s] += 0.5 * Re tr(P_t K P_s K^dagger)
__device__ void ptm_acc(float* T, const cf* K){
    cf Kd[4] = {cfconj(K[0]), cfconj(K[2]), cfconj(K[1]), cfconj(K[3])};
    for (int s=0;s<4;s++){
        cf Ps[4]; pmat(s,Ps);
        cf t1[4], t2[4];
        mul2(t1, K, Ps);
        mul2(t2, t1, Kd);
        for (int t=0;t<4;t++){
            cf Pt[4]; pmat(t,Pt);
            float re = Pt[0].x*t2[0].x - Pt[0].y*t2[0].y
                     + Pt[1].x*t2[2].x - Pt[1].y*t2[2].y
                     + Pt[2].x*t2[1].x - Pt[2].y*t2[1].y
                     + Pt[3].x*t2[3].x - Pt[3].y*t2[3].y;
            T[t*4+s] += 0.5f*re;
        }
    }
}
__device__ void rmm4(float* C, const float* A, const float* B){
    for (int i=0;i<4;i++) for (int j=0;j<4;j++){
        float s=0.f;
        for (int k=0;k<4;k++) s += A[i*4+k]*B[k*4+j];
        C[i*4+j]=s;
    }
}

// prep compute: threads 0..30 fill sm[0..495] with REAL Pauli-transfer mats.
// sm[(l*10+q)*16..] = Tnoise1 * Trot(l,q); sm[480..] = Tnoise2 (N2).
__device__ void prep_compute(float* sm, const float* __restrict__ wts, int tid){
    if (tid < 31){
        const float GA = -expm1f(-2.0000000000000002e-06f);   // 1-exp(-GATE/T1)
        const float GP = -expm1f(-1.4285714285714286e-06f);   // 1-exp(-GATE/T2)
        float sa = sqrtf(1.f-GA), spp = sqrtf(1.f-GP);
        float p = (tid==30) ? 0.01f : 0.001f;
        float f = 1.f - (4.f/3.f)*p;
        float Tn[16] = {0};
        Tn[0]      = 1.f;
        Tn[1*4+1]  = spp*sa*f;
        Tn[2*4+2]  = spp*sa*f;
        Tn[3*4+3]  = (1.f-GA)*f;
        Tn[3*4+0]  = GA;
        if (tid == 30){
            for (int i=0;i<16;i++) sm[480+i] = Tn[i];
        } else {
            float phi = wts[tid*3+0], th = wts[tid*3+1], om = wts[tid*3+2];
            float ct = cosf(0.5f*th), st = sinf(0.5f*th);
            cf ep = {cosf(0.5f*(phi+om)), -sinf(0.5f*(phi+om))};
            cf em = {cosf(0.5f*(phi-om)),  sinf(0.5f*(phi-om))};
            cf U[4];
            U[0] = { ep.x*ct,  ep.y*ct};
            U[1] = {-em.x*st, -em.y*st};
            U[2] = { em.x*st, -em.y*st};
            U[3] = { ep.x*ct, -ep.y*ct};
            float Tr[16] = {0};
            ptm_acc(Tr, U);                 // unitary: single Kraus
            float S[16]; rmm4(S, Tn, Tr);   // rot first, then noise
            for (int i=0;i<16;i++) sm[tid*16+i] = S[i];
        }
    }
}

// LDS swizzle on 12-bit float index: XOR bits 9..11 into 2..4 (float4-preserving)
__device__ __forceinline__ unsigned swz(unsigned t){ return t ^ ((t>>7)&0x1Cu); }

#define ALONG_A(Mp) { _Pragma("unroll") for (int db_=0; db_<4; db_++){ \
    float a0=v[db_], a1=v[4+db_], a2=v[8+db_], a3=v[12+db_]; \
    _Pragma("unroll") for (int dp_=0; dp_<4; dp_++){ \
        v[dp_*4+db_] = (Mp)[dp_*4+0]*a0 + (Mp)[dp_*4+1]*a1 + (Mp)[dp_*4+2]*a2 + (Mp)[dp_*4+3]*a3; } } }

#define ALONG_B(Mp) { _Pragma("unroll") for (int da_=0; da_<4; da_++){ \
    float a0=v[da_*4+0], a1=v[da_*4+1], a2=v[da_*4+2], a3=v[da_*4+3]; \
    _Pragma("unroll") for (int dp_=0; dp_<4; dp_++){ \
        v[da_*4+dp_] = (Mp)[dp_*4+0]*a0 + (Mp)[dp_*4+1]*a1 + (Mp)[dp_*4+2]*a2 + (Mp)[dp_*4+3]*a3; } } }

// transposed variants (M^T applied along the axis): index M[d*4+dp] instead of M[dp*4+d]
#define ALONG_AT(Mp) { _Pragma("unroll") for (int db_=0; db_<4; db_++){ \
    float a0=v[db_], a1=v[4+db_], a2=v[8+db_], a3=v[12+db_]; \
    _Pragma("unroll") for (int dp_=0; dp_<4; dp_++){ \
        v[dp_*4+db_] = (Mp)[0*4+dp_]*a0 + (Mp)[1*4+dp_]*a1 + (Mp)[2*4+dp_]*a2 + (Mp)[3*4+dp_]*a3; } } }

#define ALONG_BT(Mp) { _Pragma("unroll") for (int da_=0; da_<4; da_++){ \
    float a0=v[da_*4+0], a1=v[da_*4+1], a2=v[da_*4+2], a3=v[da_*4+3]; \
    _Pragma("unroll") for (int dp_=0; dp_<4; dp_++){ \
        v[da_*4+dp_] = (Mp)[0*4+dp_]*a0 + (Mp)[1*4+dp_]*a1 + (Mp)[2*4+dp_]*a2 + (Mp)[3*4+dp_]*a3; } } }

#define CNOT_PERM { float t0; \
    t0=v[4];  v[4]=v[5];   v[5]=t0;  \
    t0=v[8];  v[8]=v[9];   v[9]=t0;  \
    t0=v[2];  v[2]=v[14];  v[14]=t0; \
    t0=v[3];  v[3]=v[15];  v[15]=t0; \
    t0=v[6];  v[6]=v[11];  v[11]=t0; \
    t0=v[7];  v[7]=-v[10]; v[10]=-t0; }

// shared op-chain (5 ops of one phase window). ISB selects bit tables; LAYER selects mats.
template<int LAYER, int ISB>
__device__ __forceinline__ void run_ops(float* tile, const float* sm, int tid){
    constexpr int A_PA[5] = {0,10,8,6,4}, A_PB[5] = {10,8,6,4,2};
    constexpr int B_PA[5] = {2,10,8,6,4}, B_PB[5] = {10,8,6,4,0};
#pragma unroll
    for (int i=0; i<5; i++){
        const int pa = ISB ? B_PA[i] : A_PA[i];
        const int pb = ISB ? B_PB[i] : A_PB[i];
        const int mA = (!ISB && i==0) ? LAYER*160 : -1;               // rot(l,0) on control
        const int mB = !ISB ? (LAYER*10 + i + 1)*16
                            : ((i < 4) ? (LAYER*10 + 6 + i)*16 : -1); // rot(l,6..9)
        const int lo = pa < pb ? pa : pb, hi = pa < pb ? pb : pa;
        unsigned g8 = (unsigned)tid;
        unsigned xx = ((g8 >> lo) << (lo+2)) | (g8 & ((1u<<lo)-1u));
        xx = ((xx >> hi) << (hi+2)) | (xx & ((1u<<hi)-1u));
        unsigned adr[16];
        float v[16];
#pragma unroll
        for (int d=0; d<16; d++){
            unsigned t = xx | ((unsigned)(d>>2) << pa) | ((unsigned)(d&3) << pb);
            adr[d] = swz(t);
            v[d] = tile[adr[d]];
        }
        if (mA >= 0){ const float* M = sm + mA; ALONG_A(M); }
        if (mB >= 0){ const float* M = sm + mB; ALONG_B(M); }
        CNOT_PERM
        { const float* M = sm + 480; ALONG_B(M); ALONG_A(M); }   // N2 target, N2 control
#pragma unroll
        for (int d=0; d<16; d++) tile[adr[d]] = v[d];
        __syncthreads();
    }
}

// ================= sim phase kernel (Pauli rep, fully specialized) =================
// Phase A (ISB=0): tile = bits 0..11 (qubits 0,5,4,3,2,1); block -> bits 12..19.
// Phase B (ISB=1): tile = bits 0..3 + 12..19 (qubits 0,5,9,8,7,6); block -> bits 4..11.
// DOINIT: grid 268. Blocks 0..255 = sim (init + L1 first half); block 0 caches sm->smg.
//   Blocks 256..267: adjoint transport of observable k=blk-256 through P5's window map
//   (op^T = R^T . P . N2b^T . N2a^T, ops applied i=4..0), write dense V[k][4096].
// MODE 3 (P4): after ops, compute 12 window-observable partial dots against V for this
//   block's 16 window entries -> part[k][blk]; write 8 pass-through obs; NO rho store.
template<int LAYER, int ISB, int DOINIT, int MODE>
__global__ void __launch_bounds__(256)
fused6(float* __restrict__ rho, const float* __restrict__ wts,
       float* __restrict__ smg, float* __restrict__ cvec,
       float* __restrict__ Vbuf, float* __restrict__ part)
{
    __shared__ __align__(16) float tile[4096];
    __shared__ __align__(16) float sm[496];
    __shared__ float redp[192];
    int tid = threadIdx.x;
    unsigned blk = blockIdx.x;

    if (DOINIT){
        prep_compute(sm, wts, tid);            // wave 0 only
    } else {
        if (tid < 124)
            reinterpret_cast<float4*>(sm)[tid] = reinterpret_cast<const float4*>(smg)[tid];
    }

    if constexpr (DOINIT != 0){
        if (blk >= 256){
            // ---- adjoint (V) block: v_k = W^T e_k over P5's window ----
            int k = (int)blk - 256;
            unsigned sk = ((k & 1) ? 3u : 1u) << (2*(k>>1));   // X->1, Z->3 at slot k>>1
#pragma unroll
            for (int r=0; r<16; r++){
                unsigned u = tid + 256u*r;
                tile[swz(u)] = (u == sk) ? 1.f : 0.f;
            }
            __syncthreads();                                   // sm ready + tile ready
            const int B_PA[5] = {2,10,8,6,4}, B_PB[5] = {10,8,6,4,0};
            for (int i=4; i>=0; i--){
                int pa = B_PA[i], pb = B_PB[i];
                int mB = (i < 4) ? (26 + i)*16 : -1;           // rot(2, 6+i)
                int lo = pa < pb ? pa : pb, hi = pa < pb ? pb : pa;
                unsigned g8 = (unsigned)tid;
                unsigned xx = ((g8 >> lo) << (lo+2)) | (g8 & ((1u<<lo)-1u));
                xx = ((xx >> hi) << (hi+2)) | (xx & ((1u<<hi)-1u));
                unsigned adr[16];
                float v[16];
                for (int d=0; d<16; d++){
                    unsigned t = xx | ((unsigned)(d>>2) << pa) | ((unsigned)(d&3) << pb);
                    adr[d] = swz(t);
                    v[d] = tile[adr[d]];
                }
                { const float* M = sm + 480; ALONG_AT(M); ALONG_BT(M); }  // N2a^T, N2b^T
                CNOT_PERM                                                  // self-transpose
                if (mB >= 0){ const float* M = sm + mB; ALONG_BT(M); }     // rot^T
                for (int d=0; d<16; d++) tile[adr[d]] = v[d];
                __syncthreads();
            }
#pragma unroll
            for (int r=0; r<4; r++){
                unsigned u = 4u*(tid + 256u*r);
                *reinterpret_cast<float4*>(Vbuf + k*4096 + u) =
                    *reinterpret_cast<const float4*>(&tile[swz(u)]);
            }
            return;
        }
    }

    unsigned bo = blk << (ISB ? 4 : 12);
    if (DOINIT){
        // c_s = 1 for s in {I,Z}^10 (digit bits equal), else 0
#pragma unroll
        for (int r=0; r<16; r++){
            unsigned u = tid + 256u*r;
            unsigned g = u | bo;
            unsigned e = g & 0x55555u, o = (g>>1) & 0x55555u;
            tile[swz(u)] = (e==o) ? 1.f : 0.f;
        }
    } else {
#pragma unroll
        for (int r=0; r<4; r++){
            unsigned u = 4u*(tid + 256u*r);
            unsigned g = ISB ? ((u & 15u) | ((u>>4)<<12) | bo) : (u | bo);
            *reinterpret_cast<float4*>(&tile[swz(u)]) = *reinterpret_cast<const float4*>(rho + g);
        }
    }
    __syncthreads();

    if (DOINIT && blk == 0 && tid < 124)       // cache sm for later kernels
        reinterpret_cast<float4*>(smg)[tid] = *reinterpret_cast<const float4*>(&sm[4*tid]);

    run_ops<LAYER, ISB>(tile, sm, tid);

    if (MODE == 3){
        // pass-through observables on qubits 1..4 (cvec[2..9] = X1,Z1,X2,Z2,X3,Z3,X4,Z4)
        if (blk == 0 && tid < 8){
            const unsigned TI[8] = {1024u,3072u,256u,768u,64u,192u,16u,48u};
            cvec[2 + tid] = tile[swz(TI[tid])];
        }
        // 12 window-observable partial dots: this block owns window entries blk*16+j,
        // whose values are tile[j] (swz identity for j<16).
        if (tid < 192){
            int k = tid >> 4, j = tid & 15;
            redp[tid] = Vbuf[k*4096 + (int)blk*16 + j] * tile[j];
        }
        __syncthreads();
        if (tid < 12){
            float s = 0.f;
#pragma unroll
            for (int j=0; j<16; j++) s += redp[tid*16 + j];
            part[tid*256 + (int)blk] = s;
        }
        return;                                 // rho is dead: no store
    }

#pragma unroll
    for (int r=0; r<4; r++){
        unsigned u = 4u*(tid + 256u*r);
        unsigned g = ISB ? ((u & 15u) | ((u>>4)<<12) | bo) : (u | bo);
        *reinterpret_cast<float4*>(rho + g) = *reinterpret_cast<const float4*>(&tile[swz(u)]);
    }
}

// ================= logits (grid 2048, 1 batch/block): part-reduce + feats =================
__global__ void __launch_bounds__(256)
logits_mega(const float* __restrict__ part, const float* __restrict__ cvec,
            const float* __restrict__ x, const float* __restrict__ bvec,
            const float* __restrict__ w, float* __restrict__ out)
{
    __shared__ float xs[1024];
    __shared__ float cvw[20];
    __shared__ float redl[80];
    __shared__ float redp[192];
    int tid = threadIdx.x;
    int b = (int)blockIdx.x;

    // reduce part[12][256] -> 12 window observables (L2-broadcast, 12 KB)
    if (tid < 192){
        int k = tid >> 4, j = tid & 15;
        float s = 0.f;
#pragma unroll
        for (int m=0; m<16; m++) s += part[k*256 + j*16 + m];
        redp[tid] = s;
    }
    {
        float4 xv = reinterpret_cast<const float4*>(x + (size_t)b*1024)[tid];
        float4 bv = reinterpret_cast<const float4*>(bvec)[tid];
        xs[tid*4+0] = xv.x + bv.x;
        xs[tid*4+1] = xv.y + bv.y;
        xs[tid*4+2] = xv.z + bv.z;
        xs[tid*4+3] = xv.w + bv.w;
    }
    __syncthreads();
    if (tid < 12){
        float s = 0.f;
#pragma unroll
        for (int j=0; j<16; j++) s += redp[tid*16 + j];
        const int TQ[6] = {0,5,9,8,7,6};
        int ci = 2*TQ[tid>>1] + (tid & 1);
        cvw[ci] = ((tid & 1) ? 0.96f : 1.0f) * w[ci] * s;    // readout bitflip folded into Z
    } else if (tid < 20){
        int ci = tid - 10;                                    // 2..9: pass-through qubits 1..4
        cvw[ci] = ((ci & 1) ? 0.96f : 1.0f) * w[ci] * cvec[ci];
    }

    float aX[10] = {0,0,0,0,0,0,0,0,0,0};
    float aZ[10] = {0,0,0,0,0,0,0,0,0,0};
#pragma unroll
    for (int r=0; r<4; r++){
        int m = tid + r*256;
        float xm = xs[m];
        float x2 = xm*xm;
#pragma unroll
        for (int q=0; q<10; q++){
            int bit = 1 << (9-q);
            aX[q] += xm * xs[m ^ bit];
            aZ[q] += (m & bit) ? -x2 : x2;
        }
    }
    int lane = tid & 63, wv = tid >> 6;
#pragma unroll
    for (int kk=0; kk<20; kk++){
        float v = (kk < 10) ? aX[kk] : aZ[kk-10];
        v += __shfl_down(v, 32); v += __shfl_down(v, 16); v += __shfl_down(v, 8);
        v += __shfl_down(v, 4);  v += __shfl_down(v, 2);  v += __shfl_down(v, 1);
        if (lane == 0) redl[wv*20 + kk] = v;
    }
    __syncthreads();
    if (tid == 0){
        float logit = 0.f;
#pragma unroll
        for (int q=0; q<10; q++){
            float FX = redl[q]    + redl[20+q] + redl[40+q] + redl[60+q];
            float FZ = redl[10+q] + redl[30+q] + redl[50+q] + redl[70+q];
            logit += cvw[2*q] * FX + cvw[2*q+1] * FZ;
        }
        out[b] = 1.f / (1.f + expf(-logit));
    }
}

// ================= launch =================
extern "C" void kernel_launch(void* const* d_in, const int* in_sizes, int n_in,
                              void* d_out, int out_size, void* d_ws, size_t ws_size,
                              hipStream_t stream) {
    const float* x    = (const float*)d_in[0];   // [2048,1024]
    const float* bvec = (const float*)d_in[1];   // [1024]
    const float* w    = (const float*)d_in[2];   // [20]
    const float* cw   = (const float*)d_in[3];   // [3,10,3]
    float* out = (float*)d_out;

    char* ws = (char*)d_ws;
    float* rho  = (float*)ws;                                       // 2^20 floats = 4 MB
    float* smg  = (float*)(ws + (size_t)(1u<<20)*sizeof(float));    // 496 floats (PTM cache)
    float* cvec = smg + 512;                                        // 20 floats
    float* part = cvec + 32;                                        // 12*256 floats
    float* Vbuf = part + 3072;                                      // 12*4096 floats
    (void)ws_size; (void)in_sizes; (void)n_in; (void)out_size;

    fused6<0,0,1,0><<<268, 256, 0, stream>>>(rho, cw, smg, cvec, Vbuf, part); // P0 + V blocks
    fused6<0,1,0,0><<<256, 256, 0, stream>>>(rho, cw, smg, cvec, Vbuf, part); // P1
    fused6<1,0,0,0><<<256, 256, 0, stream>>>(rho, cw, smg, cvec, Vbuf, part); // P2
    fused6<1,1,0,0><<<256, 256, 0, stream>>>(rho, cw, smg, cvec, Vbuf, part); // P3
    fused6<2,0,0,3><<<256, 256, 0, stream>>>(rho, cw, smg, cvec, Vbuf, part); // P4 + dots
    logits_mega<<<2048, 256, 0, stream>>>(part, cvec, x, bvec, w, out);
}

// Round 15
// 67.962 us; speedup vs baseline: 2.3727x; 1.0337x over previous
//
#include <hip/hip_runtime.h>
#include <hip/hip_bf16.h>
#include <math.h>

// ================= complex 2x2 helpers (prep only) =================
struct cf { float x, y; };
__device__ __forceinline__ cf cfmul(cf a, cf b){ return {a.x*b.x - a.y*b.y, a.x*b.y + a.y*b.x}; }
__device__ __forceinline__ cf cfconj(cf a){ return {a.x, -a.y}; }
__device__ __forceinline__ cf cfadd(cf a, cf b){ return {a.x+b.x, a.y+b.y}; }

__device__ __forceinline__ void pmat(int k, cf* P){
    if (k==0){ P[0]={1.f,0.f}; P[1]={0.f,0.f}; P[2]={0.f,0.f}; P[3]={1.f,0.f}; }
    else if (k==1){ P[0]={0.f,0.f}; P[1]={1.f,0.f}; P[2]={1.f,0.f}; P[3]={0.f,0.f}; }
    else if (k==2){ P[0]={0.f,0.f}; P[1]={0.f,-1.f}; P[2]={0.f,1.f}; P[3]={0.f,0.f}; }
    else { P[0]={1.f,0.f}; P[1]={0.f,0.f}; P[2]={0.f,0.f}; P[3]={-1.f,0.f}; }
}
__device__ void mul2(cf* C, const cf* A, const cf* B){
    C[0]=cfadd(cfmul(A[0],B[0]),cfmul(A[1],B[2]));
    C[1]=cfadd(cfmul(A[0],B[1]),cfmul(A[1],B[3]));
    C[2]=cfadd(cfmul(A[2],B[0]),cfmul(A[3],B[2]));
    C[3]=cfadd(cfmul(A[2],B[1]),cfmul(A[3],B[3]));
}
// T[t*4+s] += 0.5 * Re tr(P_t K P_s K^dagger)
__device__ void ptm_acc(float* T, const cf* K){
    cf Kd[4] = {cfconj(K[0]), cfconj(K[2]), cfconj(K[1]), cfconj(K[3])};
    for (int s=0;s<4;s++){
        cf Ps[4]; pmat(s,Ps);
        cf t1[4], t2[4];
        mul2(t1, K, Ps);
        mul2(t2, t1, Kd);
        for (int t=0;t<4;t++){
            cf Pt[4]; pmat(t,Pt);
            float re = Pt[0].x*t2[0].x - Pt[0].y*t2[0].y
                     + Pt[1].x*t2[2].x - Pt[1].y*t2[2].y
                     + Pt[2].x*t2[1].x - Pt[2].y*t2[1].y
                     + Pt[3].x*t2[3].x - Pt[3].y*t2[3].y;
            T[t*4+s] += 0.5f*re;
        }
    }
}
__device__ void rmm4(float* C, const float* A, const float* B){
    for (int i=0;i<4;i++) for (int j=0;j<4;j++){
        float s=0.f;
        for (int k=0;k<4;k++) s += A[i*4+k]*B[k*4+j];
        C[i*4+j]=s;
    }
}

// prep compute: threads 0..30 fill sm[0..495] with REAL Pauli-transfer mats.
// sm[(l*10+q)*16..] = Tnoise1 * Trot(l,q); sm[480..] = Tnoise2 (N2).
__device__ void prep_compute(float* sm, const float* __restrict__ wts, int tid){
    if (tid < 31){
        const float GA = -expm1f(-2.0000000000000002e-06f);   // 1-exp(-GATE/T1)
        const float GP = -expm1f(-1.4285714285714286e-06f);   // 1-exp(-GATE/T2)
        float sa = sqrtf(1.f-GA), spp = sqrtf(1.f-GP);
        float p = (tid==30) ? 0.01f : 0.001f;
        float f = 1.f - (4.f/3.f)*p;
        float Tn[16] = {0};
        Tn[0]      = 1.f;
        Tn[1*4+1]  = spp*sa*f;
        Tn[2*4+2]  = spp*sa*f;
        Tn[3*4+3]  = (1.f-GA)*f;
        Tn[3*4+0]  = GA;
        if (tid == 30){
            for (int i=0;i<16;i++) sm[480+i] = Tn[i];
        } else {
            float phi = wts[tid*3+0], th = wts[tid*3+1], om = wts[tid*3+2];
            float ct = cosf(0.5f*th), st = sinf(0.5f*th);
            cf ep = {cosf(0.5f*(phi+om)), -sinf(0.5f*(phi+om))};
            cf em = {cosf(0.5f*(phi-om)),  sinf(0.5f*(phi-om))};
            cf U[4];
            U[0] = { ep.x*ct,  ep.y*ct};
            U[1] = {-em.x*st, -em.y*st};
            U[2] = { em.x*st, -em.y*st};
            U[3] = { ep.x*ct, -ep.y*ct};
            float Tr[16] = {0};
            ptm_acc(Tr, U);                 // unitary: single Kraus
            float S[16]; rmm4(S, Tn, Tr);   // rot first, then noise
            for (int i=0;i<16;i++) sm[tid*16+i] = S[i];
        }
    }
}

// LDS swizzle on 12-bit float index: XOR bits 9..11 into 2..4 (float4-preserving)
__device__ __forceinline__ unsigned swz(unsigned t){ return t ^ ((t>>7)&0x1Cu); }

#define ALONG_A(Mp) { _Pragma("unroll") for (int db_=0; db_<4; db_++){ \
    float a0=v[db_], a1=v[4+db_], a2=v[8+db_], a3=v[12+db_]; \
    _Pragma("unroll") for (int dp_=0; dp_<4; dp_++){ \
        v[dp_*4+db_] = (Mp)[dp_*4+0]*a0 + (Mp)[dp_*4+1]*a1 + (Mp)[dp_*4+2]*a2 + (Mp)[dp_*4+3]*a3; } } }

#define ALONG_B(Mp) { _Pragma("unroll") for (int da_=0; da_<4; da_++){ \
    float a0=v[da_*4+0], a1=v[da_*4+1], a2=v[da_*4+2], a3=v[da_*4+3]; \
    _Pragma("unroll") for (int dp_=0; dp_<4; dp_++){ \
        v[da_*4+dp_] = (Mp)[dp_*4+0]*a0 + (Mp)[dp_*4+1]*a1 + (Mp)[dp_*4+2]*a2 + (Mp)[dp_*4+3]*a3; } } }

// transposed variants (M^T applied along the axis): index M[d*4+dp] instead of M[dp*4+d]
#define ALONG_AT(Mp) { _Pragma("unroll") for (int db_=0; db_<4; db_++){ \
    float a0=v[db_], a1=v[4+db_], a2=v[8+db_], a3=v[12+db_]; \
    _Pragma("unroll") for (int dp_=0; dp_<4; dp_++){ \
        v[dp_*4+db_] = (Mp)[0*4+dp_]*a0 + (Mp)[1*4+dp_]*a1 + (Mp)[2*4+dp_]*a2 + (Mp)[3*4+dp_]*a3; } } }

#define ALONG_BT(Mp) { _Pragma("unroll") for (int da_=0; da_<4; da_++){ \
    float a0=v[da_*4+0], a1=v[da_*4+1], a2=v[da_*4+2], a3=v[da_*4+3]; \
    _Pragma("unroll") for (int dp_=0; dp_<4; dp_++){ \
        v[da_*4+dp_] = (Mp)[0*4+dp_]*a0 + (Mp)[1*4+dp_]*a1 + (Mp)[2*4+dp_]*a2 + (Mp)[3*4+dp_]*a3; } } }

#define CNOT_PERM { float t0; \
    t0=v[4];  v[4]=v[5];   v[5]=t0;  \
    t0=v[8];  v[8]=v[9];   v[9]=t0;  \
    t0=v[2];  v[2]=v[14];  v[14]=t0; \
    t0=v[3];  v[3]=v[15];  v[15]=t0; \
    t0=v[6];  v[6]=v[11];  v[11]=t0; \
    t0=v[7];  v[7]=-v[10]; v[10]=-t0; }

// window bit tables
__device__ __constant__ const int cA_PA[5] = {0,10,8,6,4}, cA_PB[5] = {10,8,6,4,2};
__device__ __constant__ const int cB_PA[5] = {2,10,8,6,4}, cB_PB[5] = {10,8,6,4,0};

// shared op-chain (5 ops of one phase window). ISB selects bit tables; LAYER selects mats.
template<int LAYER, int ISB>
__device__ __forceinline__ void run_ops(float* tile, const float* sm, int tid){
#pragma unroll
    for (int i=0; i<5; i++){
        const int pa = ISB ? cB_PA[i] : cA_PA[i];
        const int pb = ISB ? cB_PB[i] : cA_PB[i];
        const int mA = (!ISB && i==0) ? LAYER*160 : -1;               // rot(l,0) on control
        const int mB = !ISB ? (LAYER*10 + i + 1)*16
                            : ((i < 4) ? (LAYER*10 + 6 + i)*16 : -1); // rot(l,6..9)
        const int lo = pa < pb ? pa : pb, hi = pa < pb ? pb : pa;
        unsigned g8 = (unsigned)tid;
        unsigned xx = ((g8 >> lo) << (lo+2)) | (g8 & ((1u<<lo)-1u));
        xx = ((xx >> hi) << (hi+2)) | (xx & ((1u<<hi)-1u));
        unsigned adr[16];
        float v[16];
#pragma unroll
        for (int d=0; d<16; d++){
            unsigned t = xx | ((unsigned)(d>>2) << pa) | ((unsigned)(d&3) << pb);
            adr[d] = swz(t);
            v[d] = tile[adr[d]];
        }
        if (mA >= 0){ const float* M = sm + mA; ALONG_A(M); }
        if (mB >= 0){ const float* M = sm + mB; ALONG_B(M); }
        CNOT_PERM
        { const float* M = sm + 480; ALONG_B(M); ALONG_A(M); }   // N2 target, N2 control
#pragma unroll
        for (int d=0; d<16; d++) tile[adr[d]] = v[d];
        __syncthreads();
    }
}

// ================= P0: dual-purpose 512-thread kernel =================
// Waves 0-3 (tid<256): sim init + L1 first half (A-layout, block -> bits 12..19).
// Waves 4-7 of blocks 0..11: adjoint transport of observable k=blk through P5's
// window map (op^T chain, reversed order) into tileV -> Vbuf[k][4096].
// Both halves execute exactly 1 + 5 __syncthreads (wave-aligned split, no deadlock).
__global__ void __launch_bounds__(512, 1)
phase0_dual(float* __restrict__ rho, const float* __restrict__ wts,
            float* __restrict__ smg, float* __restrict__ Vbuf)
{
    __shared__ __align__(16) float tileS[4096];
    __shared__ __align__(16) float tileV[4096];
    __shared__ __align__(16) float sm[496];
    int tid = threadIdx.x;
    unsigned blk = blockIdx.x;
    const bool lower = (tid < 256);
    const int lt = tid & 255;

    prep_compute(sm, wts, tid);            // wave 0 only

    if (lower){
        unsigned bo = blk << 12;
        // c_s = 1 for s in {I,Z}^10 (digit bits equal), else 0
#pragma unroll
        for (int r=0; r<16; r++){
            unsigned u = lt + 256u*r;
            unsigned g = u | bo;
            unsigned e = g & 0x55555u, o = (g>>1) & 0x55555u;
            tileS[swz(u)] = (e==o) ? 1.f : 0.f;
        }
    } else if (blk < 12){
        int k = (int)blk;
        unsigned sk = ((k & 1) ? 3u : 1u) << (2*(k>>1));   // X->1, Z->3 at slot k>>1
#pragma unroll
        for (int r=0; r<16; r++){
            unsigned u = lt + 256u*r;
            tileV[swz(u)] = (u == sk) ? 1.f : 0.f;
        }
    }
    __syncthreads();                                       // barrier A (sm + tiles ready)

    if (blk == 0 && lower && lt < 124)                     // cache sm for later kernels
        reinterpret_cast<float4*>(smg)[lt] = *reinterpret_cast<const float4*>(&sm[4*lt]);

#pragma unroll
    for (int it=0; it<5; ++it){
        if (lower){
            // sim op it (A-layout, LAYER 0)
            const int i = it;
            const int pa = cA_PA[i], pb = cA_PB[i];
            const int mA = (i==0) ? 0 : -1;
            const int mB = (i + 1)*16;
            const int lo = pa < pb ? pa : pb, hi = pa < pb ? pb : pa;
            unsigned g8 = (unsigned)lt;
            unsigned xx = ((g8 >> lo) << (lo+2)) | (g8 & ((1u<<lo)-1u));
            xx = ((xx >> hi) << (hi+2)) | (xx & ((1u<<hi)-1u));
            unsigned adr[16];
            float v[16];
#pragma unroll
            for (int d=0; d<16; d++){
                unsigned t = xx | ((unsigned)(d>>2) << pa) | ((unsigned)(d&3) << pb);
                adr[d] = swz(t);
                v[d] = tileS[adr[d]];
            }
            if (mA >= 0){ const float* M = sm + mA; ALONG_A(M); }
            { const float* M = sm + mB; ALONG_B(M); }
            CNOT_PERM
            { const float* M = sm + 480; ALONG_B(M); ALONG_A(M); }
#pragma unroll
            for (int d=0; d<16; d++) tileS[adr[d]] = v[d];
        } else if (blk < 12){
            // adjoint op (reverse order): i = 4-it
            const int i = 4 - it;
            const int pa = cB_PA[i], pb = cB_PB[i];
            const int mB = (i < 4) ? (26 + i)*16 : -1;     // rot(2, 6+i)
            const int lo = pa < pb ? pa : pb, hi = pa < pb ? pb : pa;
            unsigned g8 = (unsigned)lt;
            unsigned xx = ((g8 >> lo) << (lo+2)) | (g8 & ((1u<<lo)-1u));
            xx = ((xx >> hi) << (hi+2)) | (xx & ((1u<<hi)-1u));
            unsigned adr[16];
            float v[16];
#pragma unroll
            for (int d=0; d<16; d++){
                unsigned t = xx | ((unsigned)(d>>2) << pa) | ((unsigned)(d&3) << pb);
                adr[d] = swz(t);
                v[d] = tileV[adr[d]];
            }
            { const float* M = sm + 480; ALONG_AT(M); ALONG_BT(M); }  // N2a^T, N2b^T
            CNOT_PERM                                                  // self-transpose
            if (mB >= 0){ const float* M = sm + mB; ALONG_BT(M); }     // rot^T
#pragma unroll
            for (int d=0; d<16; d++) tileV[adr[d]] = v[d];
        }
        __syncthreads();
    }

    if (lower){
        unsigned bo = blk << 12;
#pragma unroll
        for (int r=0; r<4; r++){
            unsigned u = 4u*(lt + 256u*r);
            *reinterpret_cast<float4*>(rho + (u | bo)) =
                *reinterpret_cast<const float4*>(&tileS[swz(u)]);
        }
    } else if (blk < 12){
#pragma unroll
        for (int r=0; r<4; r++){
            unsigned u = 4u*(lt + 256u*r);
            *reinterpret_cast<float4*>(Vbuf + (int)blk*4096 + u) =
                *reinterpret_cast<const float4*>(&tileV[swz(u)]);
        }
    }
}

// ================= sim phase kernel P1..P4 (Pauli rep, fully specialized) =================
// Phase A (ISB=0): tile = bits 0..11 (qubits 0,5,4,3,2,1); block -> bits 12..19.
// Phase B (ISB=1): tile = bits 0..3 + 12..19 (qubits 0,5,9,8,7,6); block -> bits 4..11.
// MODE 3 (P4): after ops, 12 window-observable partial dots against V -> part[k][blk];
//   block 0 writes 8 pass-through obs; NO rho store.
template<int LAYER, int ISB, int MODE>
__global__ void __launch_bounds__(256)
fused6(float* __restrict__ rho, const float* __restrict__ smg, float* __restrict__ cvec,
       const float* __restrict__ Vbuf, float* __restrict__ part)
{
    __shared__ __align__(16) float tile[4096];
    __shared__ __align__(16) float sm[496];
    __shared__ float redp[192];
    int tid = threadIdx.x;
    unsigned blk = blockIdx.x;

    if (tid < 124)
        reinterpret_cast<float4*>(sm)[tid] = reinterpret_cast<const float4*>(smg)[tid];

    unsigned bo = blk << (ISB ? 4 : 12);
#pragma unroll
    for (int r=0; r<4; r++){
        unsigned u = 4u*(tid + 256u*r);
        unsigned g = ISB ? ((u & 15u) | ((u>>4)<<12) | bo) : (u | bo);
        *reinterpret_cast<float4*>(&tile[swz(u)]) = *reinterpret_cast<const float4*>(rho + g);
    }
    __syncthreads();

    run_ops<LAYER, ISB>(tile, sm, tid);

    if (MODE == 3){
        // pass-through observables on qubits 1..4 (cvec[2..9] = X1,Z1,X2,Z2,X3,Z3,X4,Z4)
        if (blk == 0 && tid < 8){
            const unsigned TI[8] = {1024u,3072u,256u,768u,64u,192u,16u,48u};
            cvec[2 + tid] = tile[swz(TI[tid])];
        }
        // 12 window-observable partial dots: this block owns window entries blk*16+j,
        // whose values are tile[j] (swz identity for j<16).
        if (tid < 192){
            int k = tid >> 4, j = tid & 15;
            redp[tid] = Vbuf[k*4096 + (int)blk*16 + j] * tile[j];
        }
        __syncthreads();
        if (tid < 12){
            float s = 0.f;
#pragma unroll
            for (int j=0; j<16; j++) s += redp[tid*16 + j];
            part[tid*256 + (int)blk] = s;
        }
        return;                                 // rho is dead: no store
    }

#pragma unroll
    for (int r=0; r<4; r++){
        unsigned u = 4u*(tid + 256u*r);
        unsigned g = ISB ? ((u & 15u) | ((u>>4)<<12) | bo) : (u | bo);
        *reinterpret_cast<float4*>(rho + g) = *reinterpret_cast<const float4*>(&tile[swz(u)]);
    }
}

// ================= logits (grid 2048, 1 batch/block): part-reduce + feats =================
__global__ void __launch_bounds__(256)
logits_mega(const float* __restrict__ part, const float* __restrict__ cvec,
            const float* __restrict__ x, const float* __restrict__ bvec,
            const float* __restrict__ w, float* __restrict__ out)
{
    __shared__ float xs[1024];
    __shared__ float cvw[20];
    __shared__ float redl[80];
    __shared__ float redp[192];
    int tid = threadIdx.x;
    int b = (int)blockIdx.x;

    // reduce part[12][256] -> 12 window observables (L2-broadcast, 12 KB)
    if (tid < 192){
        int k = tid >> 4, j = tid & 15;
        float s = 0.f;
#pragma unroll
        for (int m=0; m<16; m++) s += part[k*256 + j*16 + m];
        redp[tid] = s;
    }
    {
        float4 xv = reinterpret_cast<const float4*>(x + (size_t)b*1024)[tid];
        float4 bv = reinterpret_cast<const float4*>(bvec)[tid];
        xs[tid*4+0] = xv.x + bv.x;
        xs[tid*4+1] = xv.y + bv.y;
        xs[tid*4+2] = xv.z + bv.z;
        xs[tid*4+3] = xv.w + bv.w;
    }
    __syncthreads();
    if (tid < 12){
        float s = 0.f;
#pragma unroll
        for (int j=0; j<16; j++) s += redp[tid*16 + j];
        const int TQ[6] = {0,5,9,8,7,6};
        int ci = 2*TQ[tid>>1] + (tid & 1);
        cvw[ci] = ((tid & 1) ? 0.96f : 1.0f) * w[ci] * s;    // readout bitflip folded into Z
    } else if (tid < 20){
        int ci = tid - 10;                                    // 2..9: pass-through qubits 1..4
        cvw[ci] = ((ci & 1) ? 0.96f : 1.0f) * w[ci] * cvec[ci];
    }

    float aX[10] = {0,0,0,0,0,0,0,0,0,0};
    float aZ[10] = {0,0,0,0,0,0,0,0,0,0};
#pragma unroll
    for (int r=0; r<4; r++){
        int m = tid + r*256;
        float xm = xs[m];
        float x2 = xm*xm;
#pragma unroll
        for (int q=0; q<10; q++){
            int bit = 1 << (9-q);
            aX[q] += xm * xs[m ^ bit];
            aZ[q] += (m & bit) ? -x2 : x2;
        }
    }
    int lane = tid & 63, wv = tid >> 6;
#pragma unroll
    for (int kk=0; kk<20; kk++){
        float v = (kk < 10) ? aX[kk] : aZ[kk-10];
        v += __shfl_down(v, 32); v += __shfl_down(v, 16); v += __shfl_down(v, 8);
        v += __shfl_down(v, 4);  v += __shfl_down(v, 2);  v += __shfl_down(v, 1);
        if (lane == 0) redl[wv*20 + kk] = v;
    }
    __syncthreads();
    if (tid == 0){
        float logit = 0.f;
#pragma unroll
        for (int q=0; q<10; q++){
            float FX = redl[q]    + redl[20+q] + redl[40+q] + redl[60+q];
            float FZ = redl[10+q] + redl[30+q] + redl[50+q] + redl[70+q];
            logit += cvw[2*q] * FX + cvw[2*q+1] * FZ;
        }
        out[b] = 1.f / (1.f + expf(-logit));
    }
}

// ================= launch =================
extern "C" void kernel_launch(void* const* d_in, const int* in_sizes, int n_in,
                              void* d_out, int out_size, void* d_ws, size_t ws_size,
                              hipStream_t stream) {
    const float* x    = (const float*)d_in[0];   // [2048,1024]
    const float* bvec = (const float*)d_in[1];   // [1024]
    const float* w    = (const float*)d_in[2];   // [20]
    const float* cw   = (const float*)d_in[3];   // [3,10,3]
    float* out = (float*)d_out;

    char* ws = (char*)d_ws;
    float* rho  = (float*)ws;                                       // 2^20 floats = 4 MB
    float* smg  = (float*)(ws + (size_t)(1u<<20)*sizeof(float));    // 496 floats (PTM cache)
    float* cvec = smg + 512;                                        // 20 floats
    float* part = cvec + 32;                                        // 12*256 floats
    float* Vbuf = part + 3072;                                      // 12*4096 floats
    (void)ws_size; (void)in_sizes; (void)n_in; (void)out_size;

    phase0_dual<<<256, 512, 0, stream>>>(rho, cw, smg, Vbuf);          // P0 sim + V (idle waves)
    fused6<0,1,0><<<256, 256, 0, stream>>>(rho, smg, cvec, Vbuf, part); // P1
    fused6<1,0,0><<<256, 256, 0, stream>>>(rho, smg, cvec, Vbuf, part); // P2
    fused6<1,1,0><<<256, 256, 0, stream>>>(rho, smg, cvec, Vbuf, part); // P3
    fused6<2,0,3><<<256, 256, 0, stream>>>(rho, smg, cvec, Vbuf, part); // P4 + dots
    logits_mega<<<2048, 256, 0, stream>>>(part, cvec, x, bvec, w, out);
}